// Round 13
// baseline (697.687 us; speedup 1.0000x reference)
//
#include <hip/hip_runtime.h>
#include <cfloat>

#define N_NODES 50000
#define N_EDGES 800000
#define E_TOT   850000
#define NG      128
#define NH      4
#define CHUNK   782   // ceil(N_NODES/64) for the 64-block scan
#define NB      782   // dst buckets of 64 nodes (d>>6)

typedef float f4 __attribute__((ext_vector_type(4)));
typedef float v4f __attribute__((ext_vector_type(4)));
typedef _Float16 h8v __attribute__((ext_vector_type(8)));

// ---------------- CSR build (by destination) ----------------
__global__ void count_dst_k(const int* __restrict__ ei, int* __restrict__ cnt) {
    int e = blockIdx.x * blockDim.x + threadIdx.x;
    if (e >= E_TOT) return;
    int d = (e < N_EDGES) ? ei[N_EDGES + e] : (e - N_EDGES);
    atomicAdd(&cnt[d], 1);
}

__global__ void scan_sums_k(const int* __restrict__ cnt, int* __restrict__ bsum) {
    int b = blockIdx.x;
    int start = b * CHUNK, end2 = min(start + CHUNK, N_NODES);
    int lane = threadIdx.x & 63, wv = threadIdx.x >> 6;
    int s = 0;
    for (int i = start + threadIdx.x; i < end2; i += 256) s += cnt[i];
    #pragma unroll
    for (int off = 32; off; off >>= 1) s += __shfl_xor(s, off);
    __shared__ int ws[4];
    if (lane == 0) ws[wv] = s;
    __syncthreads();
    if (threadIdx.x == 0) bsum[b] = ws[0] + ws[1] + ws[2] + ws[3];
}

__global__ void scan_off_k(int* __restrict__ bsum, int* __restrict__ row_ptr) {
    int lane = threadIdx.x;  // 64 threads
    int v = bsum[lane];
    int s = v;
    #pragma unroll
    for (int off = 1; off < 64; off <<= 1) {
        int t = __shfl_up(s, off);
        if (lane >= off) s += t;
    }
    bsum[lane] = s - v;  // exclusive
    if (lane == 63) row_ptr[N_NODES] = s;
}

__global__ void scan_write_k(const int* __restrict__ cnt, const int* __restrict__ bsum,
                             int* __restrict__ row_ptr) {
    int b = blockIdx.x;
    int start = b * CHUNK, end2 = min(start + CHUNK, N_NODES);
    __shared__ int wsum[4];
    __shared__ int carry_sh;
    int lane = threadIdx.x & 63, wv = threadIdx.x >> 6;
    if (threadIdx.x == 0) carry_sh = bsum[b];
    __syncthreads();
    for (int base = start; base < end2; base += 256) {
        int i = base + threadIdx.x;
        int v = (i < end2) ? cnt[i] : 0;
        int s = v;
        #pragma unroll
        for (int off = 1; off < 64; off <<= 1) {
            int t = __shfl_up(s, off);
            if (lane >= off) s += t;
        }
        if (lane == 63) wsum[wv] = s;
        __syncthreads();
        int woff = 0;
        #pragma unroll
        for (int k = 0; k < 4; ++k) if (k < wv) woff += wsum[k];
        int carry = carry_sh;
        if (i < end2) row_ptr[i] = carry + woff + s - v;
        __syncthreads();
        if (threadIdx.x == 0) carry_sh = carry + wsum[0] + wsum[1] + wsum[2] + wsum[3];
        __syncthreads();
    }
}

// bucket cursors: bcur[b] = row_ptr[b*64]
__global__ void binit_k(const int* __restrict__ row_ptr, int* __restrict__ bcur) {
    int b = blockIdx.x * blockDim.x + threadIdx.x;
    if (b < NB) bcur[b] = row_ptr[b << 6];
}

// pass 1: append (rel,src) to dst bucket — tail-sequential writes, line-local
__global__ void fill_a_k(const int* __restrict__ ei, int* __restrict__ bcur,
                         int* __restrict__ tmp) {
    int e = blockIdx.x * blockDim.x + threadIdx.x;
    if (e >= E_TOT) return;
    int s, d;
    if (e < N_EDGES) { s = ei[e]; d = ei[N_EDGES + e]; }
    else { s = e - N_EDGES; d = s; }
    int b = d >> 6;
    int slot = atomicAdd(&bcur[b], 1);
    tmp[slot] = ((d & 63) << 16) | s;   // s < 65536, rel < 64
}

// pass 2: per-bucket scatter with LDS cursors — col writes land in a ~4 KB window
__global__ void fill_b_k(const int* __restrict__ row_ptr, const int* __restrict__ tmp,
                         int* __restrict__ col) {
    __shared__ int lcur[64];
    int b = blockIdx.x;
    int n0 = b << 6;
    int n1 = min(n0 + 64, N_NODES);
    int base = row_ptr[n0], end2 = row_ptr[n1];
    if (threadIdx.x < n1 - n0) lcur[threadIdx.x] = row_ptr[n0 + threadIdx.x];
    __syncthreads();
    for (int i = base + threadIdx.x; i < end2; i += 256) {
        int v = tmp[i];
        int rel = v >> 16;
        int s = v & 0xFFFF;
        int slot = atomicAdd(&lcur[rel], 1);
        col[slot] = s;
    }
}

// ---------------- pack W (fp32 KxNOUT) into MFMA B-fragment order, fp16 ----------------
template<int K, int NOUT>
__global__ void pack_w_k(const float* __restrict__ W, _Float16* __restrict__ Wp) {
    constexpr int total = (NOUT / 16) * (K / 32) * 64;
    int t = blockIdx.x * blockDim.x + threadIdx.x;
    if (t >= total) return;
    int lane = t & 63;
    int rest = t >> 6;
    int ks = rest % (K / 32);
    int n  = rest / (K / 32);
    int colW = n * 16 + (lane & 15);
    int krow = ks * 32 + (lane >> 4) * 8;
    h8v v;
    #pragma unroll
    for (int j = 0; j < 8; ++j) v[j] = (_Float16)W[(size_t)(krow + j) * NOUT + colW];
    *(h8v*)(Wp + (size_t)t * 8) = v;
}

// fold a_src/a_dst into the extra score tile (tile NT)
template<int K, int NOUT>
__global__ void pack_a_k(const float* __restrict__ W, const float* __restrict__ asrc,
                         const float* __restrict__ adst, _Float16* __restrict__ Wp) {
    constexpr int KS = K / 32;
    constexpr int NT = NOUT / 16;
    constexpr int Fo = NOUT / NH;
    int t = blockIdx.x * blockDim.x + threadIdx.x;
    if (t >= KS * 64) return;
    int ks = t >> 6, lane = t & 63;
    int colL = lane & 15;
    int krow = ks * 32 + ((lane >> 4) & 3) * 8;
    h8v v = {};
    if (colL < 8) {
        int hd = colL & 3;
        const float* av = (colL < 4) ? asrc : adst;
        #pragma unroll
        for (int j = 0; j < 8; ++j) {
            float s = 0.f;
            const float* wr = W + (size_t)(krow + j) * NOUT + hd * Fo;
            for (int f = 0; f < Fo; ++f) s += wr[f] * av[hd * Fo + f];
            v[j] = (_Float16)s;
        }
    }
    *(h8v*)(Wp + (size_t)((NT * KS + ks) * 64 + lane) * 8) = v;
}

// ---------------- MFMA GEMM; h slice-major fp16 + scores via folded tile ----------------
template<int K, int NOUT, typename XT>
__global__ __launch_bounds__(256) void gemm_k(const XT* __restrict__ x,
                                              const _Float16* __restrict__ Wp,
                                              _Float16* __restrict__ outh,
                                              float* __restrict__ ssrc,
                                              float* __restrict__ sdst) {
    constexpr int SLICE = NOUT / 8;
    constexpr int KS  = K / 32;
    constexpr int NT  = NOUT / 16;
    constexpr int LK  = K + 8;
    __shared__ __align__(16) _Float16 xs[64 * LK];
    int row0 = blockIdx.x * 64;
    for (int seg = threadIdx.x; seg < 64 * K / 8; seg += 256) {
        int r = seg / (K / 8);
        int c = (seg % (K / 8)) * 8;
        h8v v = {};
        if (row0 + r < N_NODES) {
            if constexpr (sizeof(XT) == 2) {
                v = *(const h8v*)((const _Float16*)x + (size_t)(row0 + r) * K + c);
            } else {
                const float* xp = (const float*)x + (size_t)(row0 + r) * K + c;
                float4 a = *(const float4*)xp;
                float4 b = *(const float4*)(xp + 4);
                v[0] = (_Float16)a.x; v[1] = (_Float16)a.y;
                v[2] = (_Float16)a.z; v[3] = (_Float16)a.w;
                v[4] = (_Float16)b.x; v[5] = (_Float16)b.y;
                v[6] = (_Float16)b.z; v[7] = (_Float16)b.w;
            }
        }
        *(h8v*)(xs + r * LK + c) = v;
    }
    __syncthreads();
    int wv = threadIdx.x >> 6, lane = threadIdx.x & 63;
    int quad = lane >> 4, colL = lane & 15;
    int r0 = row0 + wv * 16;
    h8v afr[KS];
    #pragma unroll
    for (int ks = 0; ks < KS; ++ks)
        afr[ks] = *(const h8v*)(xs + (wv * 16 + colL) * LK + ks * 32 + quad * 8);
    const h8v* bp = (const h8v*)Wp;
    #pragma unroll
    for (int t = 0; t <= NT; ++t) {
        v4f acc = {};
        #pragma unroll
        for (int ks = 0; ks < KS; ++ks) {
            h8v bfr = bp[(size_t)(t * KS + ks) * 64 + lane];
            acc = __builtin_amdgcn_mfma_f32_16x16x32_f16(afr[ks], bfr, acc, 0, 0, 0);
        }
        if (t < NT) {
            int n0 = t * 16;
            int col = n0 + colL;
            int sl = n0 / SLICE;
            int so = col % SLICE;
            _Float16* op = outh + (size_t)sl * N_NODES * SLICE + so;
            #pragma unroll
            for (int reg = 0; reg < 4; ++reg) {
                int row = r0 + quad * 4 + reg;
                if (row < N_NODES) op[(size_t)row * SLICE] = (_Float16)acc[reg];
            }
        } else if (colL < 8) {
            int hd = colL & 3;
            float* sp = (colL < 4) ? ssrc : sdst;
            #pragma unroll
            for (int reg = 0; reg < 4; ++reg) {
                int row = r0 + quad * 4 + reg;
                if (row < N_NODES) sp[row * NH + hd] = acc[reg];
            }
        }
    }
}

// ---------------- normalized softmax weights -> per-head PLANES ----------------
__global__ __launch_bounds__(256) void alpha_k(const float* __restrict__ ssrc,
                                               const float* __restrict__ sdst,
                                               const int* __restrict__ row_ptr,
                                               const int* __restrict__ col,
                                               float* __restrict__ alpha) {
    int wv = threadIdx.x >> 6, lane = threadIdx.x & 63;
    int v = blockIdx.x * 4 + wv;
    if (v >= N_NODES) return;
    int hd = lane >> 4, lg = lane & 15;
    int beg = row_ptr[v], cnt = row_ptr[v + 1] - beg;
    float sdv = sdst[v * NH + hd];
    float* pl = alpha + (size_t)hd * E_TOT + beg;

    if (cnt <= 128) {
        float er[8];
        float m = -FLT_MAX;
        #pragma unroll
        for (int i = 0; i < 8; ++i) {
            int j = lg + i * 16;
            if (j < cnt) {
                int u = col[beg + j];
                float e = ssrc[u * NH + hd] + sdv;
                e = (e > 0.f) ? e : 0.2f * e;
                er[i] = e;
                m = fmaxf(m, e);
            }
        }
        #pragma unroll
        for (int off = 1; off < 16; off <<= 1) m = fmaxf(m, __shfl_xor(m, off));
        float den = 0.f;
        #pragma unroll
        for (int i = 0; i < 8; ++i) {
            int j = lg + i * 16;
            if (j < cnt) { float w = __expf(er[i] - m); er[i] = w; den += w; }
        }
        #pragma unroll
        for (int off = 1; off < 16; off <<= 1) den += __shfl_xor(den, off);
        float inv = 1.f / (den + 1e-16f);
        #pragma unroll
        for (int i = 0; i < 8; ++i) {
            int j = lg + i * 16;
            if (j < cnt) pl[j] = er[i] * inv;
        }
    } else {
        float m = -FLT_MAX;
        for (int j = lg; j < cnt; j += 16) {
            int u = col[beg + j];
            float e = ssrc[u * NH + hd] + sdv;
            e = (e > 0.f) ? e : 0.2f * e;
            m = fmaxf(m, e);
        }
        #pragma unroll
        for (int off = 1; off < 16; off <<= 1) m = fmaxf(m, __shfl_xor(m, off));
        float den = 0.f;
        for (int j = lg; j < cnt; j += 16) {
            int u = col[beg + j];
            float e = ssrc[u * NH + hd] + sdv;
            e = (e > 0.f) ? e : 0.2f * e;
            den += __expf(e - m);
        }
        #pragma unroll
        for (int off = 1; off < 16; off <<= 1) den += __shfl_xor(den, off);
        float inv = 1.f / (den + 1e-16f);
        for (int j = lg; j < cnt; j += 16) {
            int u = col[beg + j];
            float e = ssrc[u * NH + hd] + sdv;
            e = (e > 0.f) ? e : 0.2f * e;
            pl[j] = __expf(e - m) * inv;
        }
    }
}

// ---------------- XCD-sharded aggregation, wave-span LDS staging ----------------
template<int HFo, int SLICE, int LPN>
__global__ __launch_bounds__(256) void agg3_k(const _Float16* __restrict__ hh,
                                              const float* __restrict__ alpha,
                                              const int* __restrict__ row_ptr,
                                              const int* __restrict__ col,
                                              const float* __restrict__ bias,
                                              _Float16* __restrict__ outH) {
    constexpr int Fo   = HFo / NH;
    constexpr int NPW  = 64 / LPN;
    constexpr int NPB  = 4 * NPW;
    constexpr int CAPW = NPW * 32;
    __shared__ int   colS[4][CAPW];
    __shared__ float awS[4][CAPW];
    int s = blockIdx.x & 7;
    int g = blockIdx.x >> 3;
    int wv = threadIdx.x >> 6, lane = threadIdx.x & 63;
    int sub = lane / LPN, lq = lane % LPN;
    int vFirst = g * NPB + wv * NPW;
    if (vFirst >= N_NODES) return;
    int vCount = min(NPW, N_NODES - vFirst);
    int hd = (s * SLICE) / Fo;
    const float* ap = alpha + (size_t)hd * E_TOT;
    int begW = row_ptr[vFirst];
    int endW = row_ptr[vFirst + vCount];
    int len = endW - begW;
    bool active = sub < vCount;
    int v = vFirst + sub;
    int beg = 0, cnt = 0;
    if (active) { beg = row_ptr[v]; cnt = row_ptr[v + 1] - beg; }
    const _Float16* hp = hh + (size_t)s * N_NODES * SLICE + lq * 8;
    float acc[8] = {};

    if (len <= CAPW) {
        for (int t = lane; t < len; t += 64) {
            colS[wv][t] = col[begW + t];
            awS[wv][t]  = ap[begW + t];
        }
        __builtin_amdgcn_wave_barrier();
        int off = beg - begW;
        int j = 0;
        for (; j + 8 <= cnt; j += 8) {
            int u[8]; float w[8]; h8v hv[8];
            #pragma unroll
            for (int i = 0; i < 8; ++i) { u[i] = colS[wv][off + j + i]; w[i] = awS[wv][off + j + i]; }
            #pragma unroll
            for (int i = 0; i < 8; ++i) hv[i] = *(const h8v*)(hp + (size_t)u[i] * SLICE);
            #pragma unroll
            for (int i = 0; i < 8; ++i)
                #pragma unroll
                for (int c = 0; c < 8; ++c) acc[c] += w[i] * (float)hv[i][c];
        }
        for (; j < cnt; ++j) {
            int u = colS[wv][off + j];
            float w = awS[wv][off + j];
            h8v hv = *(const h8v*)(hp + (size_t)u * SLICE);
            #pragma unroll
            for (int c = 0; c < 8; ++c) acc[c] += w * (float)hv[c];
        }
    } else {
        const int*   cp = col + beg;
        const float* app = ap + beg;
        for (int j = 0; j < cnt; ++j) {
            int u = cp[j];
            float w = app[j];
            h8v hv = *(const h8v*)(hp + (size_t)u * SLICE);
            #pragma unroll
            for (int c = 0; c < 8; ++c) acc[c] += w * (float)hv[c];
        }
    }
    if (active) {
        int f0 = s * SLICE + lq * 8;
        h8v res;
        #pragma unroll
        for (int c = 0; c < 8; ++c) res[c] = (_Float16)fmaxf(acc[c] + bias[f0 + c], 0.f);
        *(h8v*)(outH + (size_t)v * HFo + f0) = res;
    }
}

// ---------------- pooling (fp16 input; batch sorted -> run-length pre-agg) ----------------
__global__ void pool_k(const _Float16* __restrict__ h, const int* __restrict__ batch,
                       float* __restrict__ gsum, float* __restrict__ gmax) {
    int f = threadIdx.x;  // 256
    int n0 = blockIdx.x * 32;
    int nend = min(n0 + 32, N_NODES);
    int cur = -1;
    float sa = 0.f, ma = 0.f;
    for (int n = n0; n < nend; ++n) {
        int g = batch[n];
        float val = (float)h[(size_t)n * 256 + f];
        if (g != cur) {
            if (cur >= 0) {
                atomicAdd(&gsum[cur * 256 + f], sa);
                atomicMax((int*)&gmax[cur * 256 + f], __float_as_int(ma));
            }
            cur = g; sa = 0.f; ma = 0.f;
        }
        sa += val;
        ma = fmaxf(ma, val);
    }
    if (cur >= 0) {
        atomicAdd(&gsum[cur * 256 + f], sa);
        atomicMax((int*)&gmax[cur * 256 + f], __float_as_int(ma));
    }
}

__global__ void gcnt_k(const int* __restrict__ batch, int* __restrict__ gcnt) {
    int g = threadIdx.x;  // 128 threads
    if (g >= NG) return;
    int lo = 0, hi = N_NODES;
    while (lo < hi) { int mid = (lo + hi) >> 1; if (batch[mid] < g) lo = mid + 1; else hi = mid; }
    int b0 = lo;
    lo = 0; hi = N_NODES;
    while (lo < hi) { int mid = (lo + hi) >> 1; if (batch[mid] < g + 1) lo = mid + 1; else hi = mid; }
    gcnt[g] = lo - b0;
}

__global__ void readout_k(const float* __restrict__ gsum, const float* __restrict__ gmax,
                          const int* __restrict__ gcnt, const float* __restrict__ Wout,
                          const float* __restrict__ bout, float* __restrict__ out) {
    int g = blockIdx.x, lane = threadIdx.x;
    float inv = 1.f / fmaxf((float)gcnt[g], 1.f);
    float acc[10];
    #pragma unroll
    for (int j = 0; j < 10; ++j) acc[j] = 0.f;
    for (int f = lane; f < 512; f += 64) {
        float p = (f < 256) ? gsum[g * 256 + f] * inv : gmax[g * 256 + (f - 256)];
        #pragma unroll
        for (int j = 0; j < 10; ++j) acc[j] += p * Wout[f * 10 + j];
    }
    #pragma unroll
    for (int j = 0; j < 10; ++j) {
        float a = acc[j];
        #pragma unroll
        for (int off = 32; off; off >>= 1) a += __shfl_xor(a, off);
        if (lane == 0) out[g * 10 + j] = a + bout[j];
    }
}

extern "C" void kernel_launch(void* const* d_in, const int* in_sizes, int n_in,
                              void* d_out, int out_size, void* d_ws, size_t ws_size,
                              hipStream_t stream) {
    const float* x    = (const float*)d_in[0];
    const int*   ei   = (const int*)d_in[1];
    const int*   batch= (const int*)d_in[2];
    const float* W0   = (const float*)d_in[3];
    const float* as0  = (const float*)d_in[4];
    const float* ad0  = (const float*)d_in[5];
    const float* b0   = (const float*)d_in[6];
    const float* W1   = (const float*)d_in[7];
    const float* as1  = (const float*)d_in[8];
    const float* ad1  = (const float*)d_in[9];
    const float* b1   = (const float*)d_in[10];
    const float* W2   = (const float*)d_in[11];
    const float* as2  = (const float*)d_in[12];
    const float* ad2  = (const float*)d_in[13];
    const float* b2   = (const float*)d_in[14];
    const float* Wout = (const float*)d_in[15];
    const float* bout = (const float*)d_in[16];
    float* out = (float*)d_out;

    char* ws = (char*)d_ws;
    size_t o = 0;
    auto take = [&](size_t bytes) { size_t r = o; o += (bytes + 255) & ~(size_t)255; return r; };
    size_t cnt_o  = take((size_t)N_NODES * 4);
    size_t gsum_o = take((size_t)NG * 256 * 4);
    size_t gmax_o = take((size_t)NG * 256 * 4);
    size_t gcnt_o = take((size_t)NG * 4);
    size_t zero_bytes = o;
    size_t rp_o   = take((size_t)(N_NODES + 1) * 4);
    size_t bsum_o = take((size_t)64 * 4);
    size_t bcur_o = take((size_t)NB * 4);
    size_t tmp_o  = take((size_t)E_TOT * 4);
    size_t col_o  = take((size_t)E_TOT * 4);
    size_t ssrc_o = take((size_t)N_NODES * NH * 4);
    size_t sdst_o = take((size_t)N_NODES * NH * 4);
    size_t alp_o  = take((size_t)NH * E_TOT * 4);      // per-head alpha planes
    size_t hh_o   = take((size_t)N_NODES * 256 * 2);   // fp16 h slice-major (gather)
    size_t bufH_o = take((size_t)N_NODES * 256 * 2);   // fp16 h row-major (gemm/pool in)
    size_t wp0_o  = take((size_t)(8 + 1) * 4 * 64 * 8 * 2);   // packed W + score tile
    size_t wp1_o  = take((size_t)(16 + 1) * 4 * 64 * 8 * 2);
    size_t wp2_o  = take((size_t)(16 + 1) * 8 * 64 * 8 * 2);

    int*      cnt    = (int*)(ws + cnt_o);
    float*    gsum   = (float*)(ws + gsum_o);
    float*    gmax   = (float*)(ws + gmax_o);
    int*      gcnt   = (int*)(ws + gcnt_o);
    int*      row_ptr= (int*)(ws + rp_o);
    int*      bsum   = (int*)(ws + bsum_o);
    int*      bcur   = (int*)(ws + bcur_o);
    int*      tmp    = (int*)(ws + tmp_o);
    int*      col    = (int*)(ws + col_o);
    float*    ssrc   = (float*)(ws + ssrc_o);
    float*    sdst   = (float*)(ws + sdst_o);
    float*    alpha  = (float*)(ws + alp_o);
    _Float16* hH     = (_Float16*)(ws + hh_o);
    _Float16* bufH   = (_Float16*)(ws + bufH_o);
    _Float16* Wp0    = (_Float16*)(ws + wp0_o);
    _Float16* Wp1    = (_Float16*)(ws + wp1_o);
    _Float16* Wp2    = (_Float16*)(ws + wp2_o);

    (void)hipMemsetAsync(ws, 0, zero_bytes, stream);

    count_dst_k<<<(E_TOT + 255) / 256, 256, 0, stream>>>(ei, cnt);
    scan_sums_k<<<64, 256, 0, stream>>>(cnt, bsum);
    scan_off_k<<<1, 64, 0, stream>>>(bsum, row_ptr);
    scan_write_k<<<64, 256, 0, stream>>>(cnt, bsum, row_ptr);
    binit_k<<<(NB + 255) / 256, 256, 0, stream>>>(row_ptr, bcur);
    fill_a_k<<<(E_TOT + 255) / 256, 256, 0, stream>>>(ei, bcur, tmp);
    fill_b_k<<<NB, 256, 0, stream>>>(row_ptr, tmp, col);

    // weight packing + score-tile folds (tiny)
    pack_w_k<128, 128><<<8, 256, 0, stream>>>(W0, Wp0);
    pack_w_k<128, 256><<<16, 256, 0, stream>>>(W1, Wp1);
    pack_w_k<256, 256><<<32, 256, 0, stream>>>(W2, Wp2);
    pack_a_k<128, 128><<<1, 256, 0, stream>>>(W0, as0, ad0, Wp0);
    pack_a_k<128, 256><<<1, 256, 0, stream>>>(W1, as1, ad1, Wp1);
    pack_a_k<256, 256><<<2, 256, 0, stream>>>(W2, as2, ad2, Wp2);

    int gemm_grid  = (N_NODES + 63) / 64;
    int alpha_grid = (N_NODES + 3) / 4;
    int agg128_grid = 8 * ((N_NODES + 127) / 128);
    int agg256_grid = 8 * ((N_NODES + 63) / 64);

    // layer 0: 128 -> H4*Fo32 (128)
    gemm_k<128, 128, float><<<gemm_grid, 256, 0, stream>>>(x, Wp0, hH, ssrc, sdst);
    alpha_k<<<alpha_grid, 256, 0, stream>>>(ssrc, sdst, row_ptr, col, alpha);
    agg3_k<128, 16, 2><<<agg128_grid, 256, 0, stream>>>(hH, alpha, row_ptr, col, b0, bufH);

    // layer 1: 128 -> H4*Fo64 (256)
    gemm_k<128, 256, _Float16><<<gemm_grid, 256, 0, stream>>>(bufH, Wp1, hH, ssrc, sdst);
    alpha_k<<<alpha_grid, 256, 0, stream>>>(ssrc, sdst, row_ptr, col, alpha);
    agg3_k<256, 32, 4><<<agg256_grid, 256, 0, stream>>>(hH, alpha, row_ptr, col, b1, bufH);

    // layer 2: 256 -> H4*Fo64 (256)
    gemm_k<256, 256, _Float16><<<gemm_grid, 256, 0, stream>>>(bufH, Wp2, hH, ssrc, sdst);
    alpha_k<<<alpha_grid, 256, 0, stream>>>(ssrc, sdst, row_ptr, col, alpha);
    agg3_k<256, 32, 4><<<agg256_grid, 256, 0, stream>>>(hH, alpha, row_ptr, col, b2, bufH);

    // pooling + readout
    pool_k<<<(N_NODES + 31) / 32, 256, 0, stream>>>(bufH, batch, gsum, gmax);
    gcnt_k<<<1, 128, 0, stream>>>(batch, gcnt);
    readout_k<<<NG, 64, 0, stream>>>(gsum, gmax, gcnt, Wout, bout, out);
}

// Round 15
// 537.923 us; speedup vs baseline: 1.2970x; 1.2970x over previous
//
#include <hip/hip_runtime.h>
#include <cfloat>

#define N_NODES 50000
#define N_EDGES 800000
#define E_TOT   850000
#define NG      128
#define NH      4
#define CHUNK   782   // ceil(N_NODES/64) for the 64-block scan

typedef float f4 __attribute__((ext_vector_type(4)));
typedef float v4f __attribute__((ext_vector_type(4)));
typedef _Float16 h8v __attribute__((ext_vector_type(8)));

// ---------------- CSR build (by destination) ----------------
__global__ void count_dst_k(const int* __restrict__ ei, int* __restrict__ cnt) {
    int e = blockIdx.x * blockDim.x + threadIdx.x;
    if (e >= E_TOT) return;
    int d = (e < N_EDGES) ? ei[N_EDGES + e] : (e - N_EDGES);
    atomicAdd(&cnt[d], 1);
}

__global__ void scan_sums_k(const int* __restrict__ cnt, int* __restrict__ bsum) {
    int b = blockIdx.x;
    int start = b * CHUNK, end2 = min(start + CHUNK, N_NODES);
    int lane = threadIdx.x & 63, wv = threadIdx.x >> 6;
    int s = 0;
    for (int i = start + threadIdx.x; i < end2; i += 256) s += cnt[i];
    #pragma unroll
    for (int off = 32; off; off >>= 1) s += __shfl_xor(s, off);
    __shared__ int ws[4];
    if (lane == 0) ws[wv] = s;
    __syncthreads();
    if (threadIdx.x == 0) bsum[b] = ws[0] + ws[1] + ws[2] + ws[3];
}

__global__ void scan_off_k(int* __restrict__ bsum, int* __restrict__ row_ptr) {
    int lane = threadIdx.x;  // 64 threads
    int v = bsum[lane];
    int s = v;
    #pragma unroll
    for (int off = 1; off < 64; off <<= 1) {
        int t = __shfl_up(s, off);
        if (lane >= off) s += t;
    }
    bsum[lane] = s - v;  // exclusive
    if (lane == 63) row_ptr[N_NODES] = s;
}

__global__ void scan_write_k(const int* __restrict__ cnt, const int* __restrict__ bsum,
                             int* __restrict__ row_ptr, int* __restrict__ cursor) {
    int b = blockIdx.x;
    int start = b * CHUNK, end2 = min(start + CHUNK, N_NODES);
    __shared__ int wsum[4];
    __shared__ int carry_sh;
    int lane = threadIdx.x & 63, wv = threadIdx.x >> 6;
    if (threadIdx.x == 0) carry_sh = bsum[b];
    __syncthreads();
    for (int base = start; base < end2; base += 256) {
        int i = base + threadIdx.x;
        int v = (i < end2) ? cnt[i] : 0;
        int s = v;
        #pragma unroll
        for (int off = 1; off < 64; off <<= 1) {
            int t = __shfl_up(s, off);
            if (lane >= off) s += t;
        }
        if (lane == 63) wsum[wv] = s;
        __syncthreads();
        int woff = 0;
        #pragma unroll
        for (int k = 0; k < 4; ++k) if (k < wv) woff += wsum[k];
        int carry = carry_sh;
        if (i < end2) { int rp = carry + woff + s - v; row_ptr[i] = rp; cursor[i] = rp; }
        __syncthreads();
        if (threadIdx.x == 0) carry_sh = carry + wsum[0] + wsum[1] + wsum[2] + wsum[3];
        __syncthreads();
    }
}

// direct scatter (known-good round-12 path; 57 us, write-sector-bound)
__global__ void fill_k(const int* __restrict__ ei, int* __restrict__ cursor,
                       int* __restrict__ col) {
    int e = blockIdx.x * blockDim.x + threadIdx.x;
    if (e >= E_TOT) return;
    int s, d;
    if (e < N_EDGES) { s = ei[e]; d = ei[N_EDGES + e]; }
    else { s = e - N_EDGES; d = s; }
    int slot = atomicAdd(&cursor[d], 1);
    col[slot] = s;
}

// ---------------- pack W (fp32 KxNOUT) into MFMA B-fragment order, fp16 ----------------
template<int K, int NOUT>
__global__ void pack_w_k(const float* __restrict__ W, _Float16* __restrict__ Wp) {
    constexpr int total = (NOUT / 16) * (K / 32) * 64;
    int t = blockIdx.x * blockDim.x + threadIdx.x;
    if (t >= total) return;
    int lane = t & 63;
    int rest = t >> 6;
    int ks = rest % (K / 32);
    int n  = rest / (K / 32);
    int colW = n * 16 + (lane & 15);
    int krow = ks * 32 + (lane >> 4) * 8;
    h8v v;
    #pragma unroll
    for (int j = 0; j < 8; ++j) v[j] = (_Float16)W[(size_t)(krow + j) * NOUT + colW];
    *(h8v*)(Wp + (size_t)t * 8) = v;
}

// fold a_src/a_dst into the extra score tile (tile NT)
template<int K, int NOUT>
__global__ void pack_a_k(const float* __restrict__ W, const float* __restrict__ asrc,
                         const float* __restrict__ adst, _Float16* __restrict__ Wp) {
    constexpr int KS = K / 32;
    constexpr int NT = NOUT / 16;
    constexpr int Fo = NOUT / NH;
    int t = blockIdx.x * blockDim.x + threadIdx.x;
    if (t >= KS * 64) return;
    int ks = t >> 6, lane = t & 63;
    int colL = lane & 15;
    int krow = ks * 32 + ((lane >> 4) & 3) * 8;
    h8v v = {};
    if (colL < 8) {
        int hd = colL & 3;
        const float* av = (colL < 4) ? asrc : adst;
        #pragma unroll
        for (int j = 0; j < 8; ++j) {
            float s = 0.f;
            const float* wr = W + (size_t)(krow + j) * NOUT + hd * Fo;
            for (int f = 0; f < Fo; ++f) s += wr[f] * av[hd * Fo + f];
            v[j] = (_Float16)s;
        }
    }
    *(h8v*)(Wp + (size_t)((NT * KS + ks) * 64 + lane) * 8) = v;
}

// ---------------- MFMA GEMM; h slice-major fp16 + scores via folded tile ----------------
// blockIdx.y splits the (NT+1) tiles into 2 groups for 2x wave parallelism.
template<int K, int NOUT, typename XT>
__global__ __launch_bounds__(256) void gemm_k(const XT* __restrict__ x,
                                              const _Float16* __restrict__ Wp,
                                              _Float16* __restrict__ outh,
                                              float* __restrict__ ssrc,
                                              float* __restrict__ sdst) {
    constexpr int SLICE = NOUT / 8;
    constexpr int KS  = K / 32;
    constexpr int NT  = NOUT / 16;     // h col tiles (score tile is NT)
    constexpr int NTT = NT + 1;
    constexpr int HALF = (NTT + 1) / 2;
    constexpr int LK  = K + 8;
    __shared__ __align__(16) _Float16 xs[64 * LK];
    int row0 = blockIdx.x * 64;
    int t0 = blockIdx.y * HALF;
    int t1 = min(t0 + HALF, NTT);
    for (int seg = threadIdx.x; seg < 64 * K / 8; seg += 256) {
        int r = seg / (K / 8);
        int c = (seg % (K / 8)) * 8;
        h8v v = {};
        if (row0 + r < N_NODES) {
            if constexpr (sizeof(XT) == 2) {
                v = *(const h8v*)((const _Float16*)x + (size_t)(row0 + r) * K + c);
            } else {
                const float* xp = (const float*)x + (size_t)(row0 + r) * K + c;
                float4 a = *(const float4*)xp;
                float4 b = *(const float4*)(xp + 4);
                v[0] = (_Float16)a.x; v[1] = (_Float16)a.y;
                v[2] = (_Float16)a.z; v[3] = (_Float16)a.w;
                v[4] = (_Float16)b.x; v[5] = (_Float16)b.y;
                v[6] = (_Float16)b.z; v[7] = (_Float16)b.w;
            }
        }
        *(h8v*)(xs + r * LK + c) = v;
    }
    __syncthreads();
    int wv = threadIdx.x >> 6, lane = threadIdx.x & 63;
    int quad = lane >> 4, colL = lane & 15;
    int r0 = row0 + wv * 16;
    h8v afr[KS];
    #pragma unroll
    for (int ks = 0; ks < KS; ++ks)
        afr[ks] = *(const h8v*)(xs + (wv * 16 + colL) * LK + ks * 32 + quad * 8);
    const h8v* bp = (const h8v*)Wp;
    for (int t = t0; t < t1; ++t) {
        v4f acc = {};
        #pragma unroll
        for (int ks = 0; ks < KS; ++ks) {
            h8v bfr = bp[(size_t)(t * KS + ks) * 64 + lane];
            acc = __builtin_amdgcn_mfma_f32_16x16x32_f16(afr[ks], bfr, acc, 0, 0, 0);
        }
        if (t < NT) {
            int n0 = t * 16;
            int col = n0 + colL;
            int sl = n0 / SLICE;
            int so = col % SLICE;
            _Float16* op = outh + (size_t)sl * N_NODES * SLICE + so;
            #pragma unroll
            for (int reg = 0; reg < 4; ++reg) {
                int row = r0 + quad * 4 + reg;
                if (row < N_NODES) op[(size_t)row * SLICE] = (_Float16)acc[reg];
            }
        } else if (colL < 8) {
            int hd = colL & 3;
            float* sp = (colL < 4) ? ssrc : sdst;
            #pragma unroll
            for (int reg = 0; reg < 4; ++reg) {
                int row = r0 + quad * 4 + reg;
                if (row < N_NODES) sp[row * NH + hd] = acc[reg];
            }
        }
    }
}

// ---------------- normalized softmax weights -> per-head PLANES ----------------
__global__ __launch_bounds__(256) void alpha_k(const float* __restrict__ ssrc,
                                               const float* __restrict__ sdst,
                                               const int* __restrict__ row_ptr,
                                               const int* __restrict__ col,
                                               float* __restrict__ alpha) {
    int wv = threadIdx.x >> 6, lane = threadIdx.x & 63;
    int v = blockIdx.x * 4 + wv;
    if (v >= N_NODES) return;
    int hd = lane >> 4, lg = lane & 15;
    int beg = row_ptr[v], cnt = row_ptr[v + 1] - beg;
    float sdv = sdst[v * NH + hd];
    float* pl = alpha + (size_t)hd * E_TOT + beg;

    if (cnt <= 128) {
        float er[8];
        float m = -FLT_MAX;
        #pragma unroll
        for (int i = 0; i < 8; ++i) {
            int j = lg + i * 16;
            if (j < cnt) {
                int u = col[beg + j];
                float e = ssrc[u * NH + hd] + sdv;
                e = (e > 0.f) ? e : 0.2f * e;
                er[i] = e;
                m = fmaxf(m, e);
            }
        }
        #pragma unroll
        for (int off = 1; off < 16; off <<= 1) m = fmaxf(m, __shfl_xor(m, off));
        float den = 0.f;
        #pragma unroll
        for (int i = 0; i < 8; ++i) {
            int j = lg + i * 16;
            if (j < cnt) { float w = __expf(er[i] - m); er[i] = w; den += w; }
        }
        #pragma unroll
        for (int off = 1; off < 16; off <<= 1) den += __shfl_xor(den, off);
        float inv = 1.f / (den + 1e-16f);
        #pragma unroll
        for (int i = 0; i < 8; ++i) {
            int j = lg + i * 16;
            if (j < cnt) pl[j] = er[i] * inv;
        }
    } else {
        float m = -FLT_MAX;
        for (int j = lg; j < cnt; j += 16) {
            int u = col[beg + j];
            float e = ssrc[u * NH + hd] + sdv;
            e = (e > 0.f) ? e : 0.2f * e;
            m = fmaxf(m, e);
        }
        #pragma unroll
        for (int off = 1; off < 16; off <<= 1) m = fmaxf(m, __shfl_xor(m, off));
        float den = 0.f;
        for (int j = lg; j < cnt; j += 16) {
            int u = col[beg + j];
            float e = ssrc[u * NH + hd] + sdv;
            e = (e > 0.f) ? e : 0.2f * e;
            den += __expf(e - m);
        }
        #pragma unroll
        for (int off = 1; off < 16; off <<= 1) den += __shfl_xor(den, off);
        float inv = 1.f / (den + 1e-16f);
        for (int j = lg; j < cnt; j += 16) {
            int u = col[beg + j];
            float e = ssrc[u * NH + hd] + sdv;
            e = (e > 0.f) ? e : 0.2f * e;
            pl[j] = __expf(e - m) * inv;
        }
    }
}

// ---------------- XCD-sharded aggregation, wave-span LDS staging ----------------
template<int HFo, int SLICE, int LPN>
__global__ __launch_bounds__(256) void agg3_k(const _Float16* __restrict__ hh,
                                              const float* __restrict__ alpha,
                                              const int* __restrict__ row_ptr,
                                              const int* __restrict__ col,
                                              const float* __restrict__ bias,
                                              _Float16* __restrict__ outH) {
    constexpr int Fo   = HFo / NH;
    constexpr int NPW  = 64 / LPN;
    constexpr int NPB  = 4 * NPW;
    constexpr int CAPW = NPW * 32;
    __shared__ int   colS[4][CAPW];
    __shared__ float awS[4][CAPW];
    int s = blockIdx.x & 7;
    int g = blockIdx.x >> 3;
    int wv = threadIdx.x >> 6, lane = threadIdx.x & 63;
    int sub = lane / LPN, lq = lane % LPN;
    int vFirst = g * NPB + wv * NPW;
    if (vFirst >= N_NODES) return;
    int vCount = min(NPW, N_NODES - vFirst);
    int hd = (s * SLICE) / Fo;
    const float* ap = alpha + (size_t)hd * E_TOT;
    int begW = row_ptr[vFirst];
    int endW = row_ptr[vFirst + vCount];
    int len = endW - begW;
    bool active = sub < vCount;
    int v = vFirst + sub;
    int beg = 0, cnt = 0;
    if (active) { beg = row_ptr[v]; cnt = row_ptr[v + 1] - beg; }
    const _Float16* hp = hh + (size_t)s * N_NODES * SLICE + lq * 8;
    float acc[8] = {};

    if (len <= CAPW) {
        for (int t = lane; t < len; t += 64) {
            colS[wv][t] = col[begW + t];
            awS[wv][t]  = ap[begW + t];
        }
        __builtin_amdgcn_wave_barrier();
        int off = beg - begW;
        int j = 0;
        for (; j + 8 <= cnt; j += 8) {
            int u[8]; float w[8]; h8v hv[8];
            #pragma unroll
            for (int i = 0; i < 8; ++i) { u[i] = colS[wv][off + j + i]; w[i] = awS[wv][off + j + i]; }
            #pragma unroll
            for (int i = 0; i < 8; ++i) hv[i] = *(const h8v*)(hp + (size_t)u[i] * SLICE);
            #pragma unroll
            for (int i = 0; i < 8; ++i)
                #pragma unroll
                for (int c = 0; c < 8; ++c) acc[c] += w[i] * (float)hv[i][c];
        }
        for (; j < cnt; ++j) {
            int u = colS[wv][off + j];
            float w = awS[wv][off + j];
            h8v hv = *(const h8v*)(hp + (size_t)u * SLICE);
            #pragma unroll
            for (int c = 0; c < 8; ++c) acc[c] += w * (float)hv[c];
        }
    } else {
        const int*   cp = col + beg;
        const float* app = ap + beg;
        for (int j = 0; j < cnt; ++j) {
            int u = cp[j];
            float w = app[j];
            h8v hv = *(const h8v*)(hp + (size_t)u * SLICE);
            #pragma unroll
            for (int c = 0; c < 8; ++c) acc[c] += w * (float)hv[c];
        }
    }
    if (active) {
        int f0 = s * SLICE + lq * 8;
        h8v res;
        #pragma unroll
        for (int c = 0; c < 8; ++c) res[c] = (_Float16)fmaxf(acc[c] + bias[f0 + c], 0.f);
        *(h8v*)(outH + (size_t)v * HFo + f0) = res;
    }
}

// ---------------- pooling (fp16 input; batch sorted -> run-length pre-agg) ----------------
__global__ void pool_k(const _Float16* __restrict__ h, const int* __restrict__ batch,
                       float* __restrict__ gsum, float* __restrict__ gmax) {
    int f = threadIdx.x;  // 256
    int n0 = blockIdx.x * 32;
    int nend = min(n0 + 32, N_NODES);
    int cur = -1;
    float sa = 0.f, ma = 0.f;
    for (int n = n0; n < nend; ++n) {
        int g = batch[n];
        float val = (float)h[(size_t)n * 256 + f];
        if (g != cur) {
            if (cur >= 0) {
                atomicAdd(&gsum[cur * 256 + f], sa);
                atomicMax((int*)&gmax[cur * 256 + f], __float_as_int(ma));
            }
            cur = g; sa = 0.f; ma = 0.f;
        }
        sa += val;
        ma = fmaxf(ma, val);
    }
    if (cur >= 0) {
        atomicAdd(&gsum[cur * 256 + f], sa);
        atomicMax((int*)&gmax[cur * 256 + f], __float_as_int(ma));
    }
}

__global__ void gcnt_k(const int* __restrict__ batch, int* __restrict__ gcnt) {
    int g = threadIdx.x;  // 128 threads
    if (g >= NG) return;
    int lo = 0, hi = N_NODES;
    while (lo < hi) { int mid = (lo + hi) >> 1; if (batch[mid] < g) lo = mid + 1; else hi = mid; }
    int b0 = lo;
    lo = 0; hi = N_NODES;
    while (lo < hi) { int mid = (lo + hi) >> 1; if (batch[mid] < g + 1) lo = mid + 1; else hi = mid; }
    gcnt[g] = lo - b0;
}

__global__ void readout_k(const float* __restrict__ gsum, const float* __restrict__ gmax,
                          const int* __restrict__ gcnt, const float* __restrict__ Wout,
                          const float* __restrict__ bout, float* __restrict__ out) {
    int g = blockIdx.x, lane = threadIdx.x;
    float inv = 1.f / fmaxf((float)gcnt[g], 1.f);
    float acc[10];
    #pragma unroll
    for (int j = 0; j < 10; ++j) acc[j] = 0.f;
    for (int f = lane; f < 512; f += 64) {
        float p = (f < 256) ? gsum[g * 256 + f] * inv : gmax[g * 256 + (f - 256)];
        #pragma unroll
        for (int j = 0; j < 10; ++j) acc[j] += p * Wout[f * 10 + j];
    }
    #pragma unroll
    for (int j = 0; j < 10; ++j) {
        float a = acc[j];
        #pragma unroll
        for (int off = 32; off; off >>= 1) a += __shfl_xor(a, off);
        if (lane == 0) out[g * 10 + j] = a + bout[j];
    }
}

extern "C" void kernel_launch(void* const* d_in, const int* in_sizes, int n_in,
                              void* d_out, int out_size, void* d_ws, size_t ws_size,
                              hipStream_t stream) {
    const float* x    = (const float*)d_in[0];
    const int*   ei   = (const int*)d_in[1];
    const int*   batch= (const int*)d_in[2];
    const float* W0   = (const float*)d_in[3];
    const float* as0  = (const float*)d_in[4];
    const float* ad0  = (const float*)d_in[5];
    const float* b0   = (const float*)d_in[6];
    const float* W1   = (const float*)d_in[7];
    const float* as1  = (const float*)d_in[8];
    const float* ad1  = (const float*)d_in[9];
    const float* b1   = (const float*)d_in[10];
    const float* W2   = (const float*)d_in[11];
    const float* as2  = (const float*)d_in[12];
    const float* ad2  = (const float*)d_in[13];
    const float* b2   = (const float*)d_in[14];
    const float* Wout = (const float*)d_in[15];
    const float* bout = (const float*)d_in[16];
    float* out = (float*)d_out;

    char* ws = (char*)d_ws;
    size_t o = 0;
    auto take = [&](size_t bytes) { size_t r = o; o += (bytes + 255) & ~(size_t)255; return r; };
    size_t cnt_o  = take((size_t)N_NODES * 4);
    size_t gsum_o = take((size_t)NG * 256 * 4);
    size_t gmax_o = take((size_t)NG * 256 * 4);
    size_t gcnt_o = take((size_t)NG * 4);
    size_t zero_bytes = o;
    size_t rp_o   = take((size_t)(N_NODES + 1) * 4);
    size_t cur_o  = take((size_t)N_NODES * 4);
    size_t bsum_o = take((size_t)64 * 4);
    size_t col_o  = take((size_t)E_TOT * 4);
    size_t ssrc_o = take((size_t)N_NODES * NH * 4);
    size_t sdst_o = take((size_t)N_NODES * NH * 4);
    size_t alp_o  = take((size_t)NH * E_TOT * 4);      // per-head alpha planes
    size_t hh_o   = take((size_t)N_NODES * 256 * 2);   // fp16 h slice-major (gather)
    size_t bufH_o = take((size_t)N_NODES * 256 * 2);   // fp16 h row-major (gemm/pool in)
    size_t wp0_o  = take((size_t)(8 + 1) * 4 * 64 * 8 * 2);   // packed W + score tile
    size_t wp1_o  = take((size_t)(16 + 1) * 4 * 64 * 8 * 2);
    size_t wp2_o  = take((size_t)(16 + 1) * 8 * 64 * 8 * 2);

    int*      cnt    = (int*)(ws + cnt_o);
    float*    gsum   = (float*)(ws + gsum_o);
    float*    gmax   = (float*)(ws + gmax_o);
    int*      gcnt   = (int*)(ws + gcnt_o);
    int*      row_ptr= (int*)(ws + rp_o);
    int*      cursor = (int*)(ws + cur_o);
    int*      bsum   = (int*)(ws + bsum_o);
    int*      col    = (int*)(ws + col_o);
    float*    ssrc   = (float*)(ws + ssrc_o);
    float*    sdst   = (float*)(ws + sdst_o);
    float*    alpha  = (float*)(ws + alp_o);
    _Float16* hH     = (_Float16*)(ws + hh_o);
    _Float16* bufH   = (_Float16*)(ws + bufH_o);
    _Float16* Wp0    = (_Float16*)(ws + wp0_o);
    _Float16* Wp1    = (_Float16*)(ws + wp1_o);
    _Float16* Wp2    = (_Float16*)(ws + wp2_o);

    (void)hipMemsetAsync(ws, 0, zero_bytes, stream);

    count_dst_k<<<(E_TOT + 255) / 256, 256, 0, stream>>>(ei, cnt);
    scan_sums_k<<<64, 256, 0, stream>>>(cnt, bsum);
    scan_off_k<<<1, 64, 0, stream>>>(bsum, row_ptr);
    scan_write_k<<<64, 256, 0, stream>>>(cnt, bsum, row_ptr, cursor);
    fill_k<<<(E_TOT + 255) / 256, 256, 0, stream>>>(ei, cursor, col);

    // weight packing + score-tile folds (tiny)
    pack_w_k<128, 128><<<8, 256, 0, stream>>>(W0, Wp0);
    pack_w_k<128, 256><<<16, 256, 0, stream>>>(W1, Wp1);
    pack_w_k<256, 256><<<32, 256, 0, stream>>>(W2, Wp2);
    pack_a_k<128, 128><<<1, 256, 0, stream>>>(W0, as0, ad0, Wp0);
    pack_a_k<128, 256><<<1, 256, 0, stream>>>(W1, as1, ad1, Wp1);
    pack_a_k<256, 256><<<2, 256, 0, stream>>>(W2, as2, ad2, Wp2);

    dim3 gemm_grid((N_NODES + 63) / 64, 2);
    int alpha_grid = (N_NODES + 3) / 4;
    int agg128_grid = 8 * ((N_NODES + 127) / 128);
    int agg256_grid = 8 * ((N_NODES + 63) / 64);

    // layer 0: 128 -> H4*Fo32 (128)
    gemm_k<128, 128, float><<<gemm_grid, 256, 0, stream>>>(x, Wp0, hH, ssrc, sdst);
    alpha_k<<<alpha_grid, 256, 0, stream>>>(ssrc, sdst, row_ptr, col, alpha);
    agg3_k<128, 16, 2><<<agg128_grid, 256, 0, stream>>>(hH, alpha, row_ptr, col, b0, bufH);

    // layer 1: 128 -> H4*Fo64 (256)
    gemm_k<128, 256, _Float16><<<gemm_grid, 256, 0, stream>>>(bufH, Wp1, hH, ssrc, sdst);
    alpha_k<<<alpha_grid, 256, 0, stream>>>(ssrc, sdst, row_ptr, col, alpha);
    agg3_k<256, 32, 4><<<agg256_grid, 256, 0, stream>>>(hH, alpha, row_ptr, col, b1, bufH);

    // layer 2: 256 -> H4*Fo64 (256)
    gemm_k<256, 256, _Float16><<<gemm_grid, 256, 0, stream>>>(bufH, Wp2, hH, ssrc, sdst);
    alpha_k<<<alpha_grid, 256, 0, stream>>>(ssrc, sdst, row_ptr, col, alpha);
    agg3_k<256, 32, 4><<<agg256_grid, 256, 0, stream>>>(hH, alpha, row_ptr, col, b2, bufH);

    // pooling + readout
    pool_k<<<(N_NODES + 31) / 32, 256, 0, stream>>>(bufH, batch, gsum, gmax);
    gcnt_k<<<1, 128, 0, stream>>>(batch, gcnt);
    readout_k<<<NG, 64, 0, stream>>>(gsum, gmax, gcnt, Wout, bout, out);
}

// Round 16
// 519.342 us; speedup vs baseline: 1.3434x; 1.0358x over previous
//
#include <hip/hip_runtime.h>
#include <cfloat>

#define N_NODES 50000
#define N_EDGES 800000
#define E_TOT   850000
#define NG      128
#define NH      4
#define CHUNK   782   // ceil(N_NODES/64) for the 64-block scan

typedef float f4 __attribute__((ext_vector_type(4)));
typedef float v4f __attribute__((ext_vector_type(4)));
typedef _Float16 h8v __attribute__((ext_vector_type(8)));

// ---------------- CSR build (by destination) ----------------
__global__ void count_dst_k(const int* __restrict__ ei, int* __restrict__ cnt) {
    int e = blockIdx.x * blockDim.x + threadIdx.x;
    if (e >= E_TOT) return;
    int d = (e < N_EDGES) ? ei[N_EDGES + e] : (e - N_EDGES);
    atomicAdd(&cnt[d], 1);
}

__global__ void scan_sums_k(const int* __restrict__ cnt, int* __restrict__ bsum) {
    int b = blockIdx.x;
    int start = b * CHUNK, end2 = min(start + CHUNK, N_NODES);
    int lane = threadIdx.x & 63, wv = threadIdx.x >> 6;
    int s = 0;
    for (int i = start + threadIdx.x; i < end2; i += 256) s += cnt[i];
    #pragma unroll
    for (int off = 32; off; off >>= 1) s += __shfl_xor(s, off);
    __shared__ int ws[4];
    if (lane == 0) ws[wv] = s;
    __syncthreads();
    if (threadIdx.x == 0) bsum[b] = ws[0] + ws[1] + ws[2] + ws[3];
}

__global__ void scan_off_k(int* __restrict__ bsum, int* __restrict__ row_ptr) {
    int lane = threadIdx.x;  // 64 threads
    int v = bsum[lane];
    int s = v;
    #pragma unroll
    for (int off = 1; off < 64; off <<= 1) {
        int t = __shfl_up(s, off);
        if (lane >= off) s += t;
    }
    bsum[lane] = s - v;  // exclusive
    if (lane == 63) row_ptr[N_NODES] = s;
}

__global__ void scan_write_k(const int* __restrict__ cnt, const int* __restrict__ bsum,
                             int* __restrict__ row_ptr, int* __restrict__ cursor) {
    int b = blockIdx.x;
    int start = b * CHUNK, end2 = min(start + CHUNK, N_NODES);
    __shared__ int wsum[4];
    __shared__ int carry_sh;
    int lane = threadIdx.x & 63, wv = threadIdx.x >> 6;
    if (threadIdx.x == 0) carry_sh = bsum[b];
    __syncthreads();
    for (int base = start; base < end2; base += 256) {
        int i = base + threadIdx.x;
        int v = (i < end2) ? cnt[i] : 0;
        int s = v;
        #pragma unroll
        for (int off = 1; off < 64; off <<= 1) {
            int t = __shfl_up(s, off);
            if (lane >= off) s += t;
        }
        if (lane == 63) wsum[wv] = s;
        __syncthreads();
        int woff = 0;
        #pragma unroll
        for (int k = 0; k < 4; ++k) if (k < wv) woff += wsum[k];
        int carry = carry_sh;
        if (i < end2) { int rp = carry + woff + s - v; row_ptr[i] = rp; cursor[i] = rp; }
        __syncthreads();
        if (threadIdx.x == 0) carry_sh = carry + wsum[0] + wsum[1] + wsum[2] + wsum[3];
        __syncthreads();
    }
}

// direct scatter (known-good; write-sector-bound ~57 us)
__global__ void fill_k(const int* __restrict__ ei, int* __restrict__ cursor,
                       int* __restrict__ col) {
    int e = blockIdx.x * blockDim.x + threadIdx.x;
    if (e >= E_TOT) return;
    int s, d;
    if (e < N_EDGES) { s = ei[e]; d = ei[N_EDGES + e]; }
    else { s = e - N_EDGES; d = s; }
    int slot = atomicAdd(&cursor[d], 1);
    col[slot] = s;
}

// ---------------- pack W (fp32 KxNOUT) into MFMA B-fragment order, fp16 ----------------
template<int K, int NOUT>
__global__ void pack_w_k(const float* __restrict__ W, _Float16* __restrict__ Wp) {
    constexpr int total = (NOUT / 16) * (K / 32) * 64;
    int t = blockIdx.x * blockDim.x + threadIdx.x;
    if (t >= total) return;
    int lane = t & 63;
    int rest = t >> 6;
    int ks = rest % (K / 32);
    int n  = rest / (K / 32);
    int colW = n * 16 + (lane & 15);
    int krow = ks * 32 + (lane >> 4) * 8;
    h8v v;
    #pragma unroll
    for (int j = 0; j < 8; ++j) v[j] = (_Float16)W[(size_t)(krow + j) * NOUT + colW];
    *(h8v*)(Wp + (size_t)t * 8) = v;
}

// fold a_src/a_dst into the extra score tile (tile NT)
template<int K, int NOUT>
__global__ void pack_a_k(const float* __restrict__ W, const float* __restrict__ asrc,
                         const float* __restrict__ adst, _Float16* __restrict__ Wp) {
    constexpr int KS = K / 32;
    constexpr int NT = NOUT / 16;
    constexpr int Fo = NOUT / NH;
    int t = blockIdx.x * blockDim.x + threadIdx.x;
    if (t >= KS * 64) return;
    int ks = t >> 6, lane = t & 63;
    int colL = lane & 15;
    int krow = ks * 32 + ((lane >> 4) & 3) * 8;
    h8v v = {};
    if (colL < 8) {
        int hd = colL & 3;
        const float* av = (colL < 4) ? asrc : adst;
        #pragma unroll
        for (int j = 0; j < 8; ++j) {
            float s = 0.f;
            const float* wr = W + (size_t)(krow + j) * NOUT + hd * Fo;
            for (int f = 0; f < Fo; ++f) s += wr[f] * av[hd * Fo + f];
            v[j] = (_Float16)s;
        }
    }
    *(h8v*)(Wp + (size_t)((NT * KS + ks) * 64 + lane) * 8) = v;
}

// ---------------- MFMA GEMM; h slice-major fp16 + scores via folded tile ----------------
template<int K, int NOUT, typename XT>
__global__ __launch_bounds__(256) void gemm_k(const XT* __restrict__ x,
                                              const _Float16* __restrict__ Wp,
                                              _Float16* __restrict__ outh,
                                              float* __restrict__ ssrc,
                                              float* __restrict__ sdst) {
    constexpr int SLICE = NOUT / 8;
    constexpr int KS  = K / 32;
    constexpr int NT  = NOUT / 16;
    constexpr int LK  = K + 8;
    __shared__ __align__(16) _Float16 xs[64 * LK];
    int row0 = blockIdx.x * 64;
    for (int seg = threadIdx.x; seg < 64 * K / 8; seg += 256) {
        int r = seg / (K / 8);
        int c = (seg % (K / 8)) * 8;
        h8v v = {};
        if (row0 + r < N_NODES) {
            if constexpr (sizeof(XT) == 2) {
                v = *(const h8v*)((const _Float16*)x + (size_t)(row0 + r) * K + c);
            } else {
                const float* xp = (const float*)x + (size_t)(row0 + r) * K + c;
                float4 a = *(const float4*)xp;
                float4 b = *(const float4*)(xp + 4);
                v[0] = (_Float16)a.x; v[1] = (_Float16)a.y;
                v[2] = (_Float16)a.z; v[3] = (_Float16)a.w;
                v[4] = (_Float16)b.x; v[5] = (_Float16)b.y;
                v[6] = (_Float16)b.z; v[7] = (_Float16)b.w;
            }
        }
        *(h8v*)(xs + r * LK + c) = v;
    }
    __syncthreads();
    int wv = threadIdx.x >> 6, lane = threadIdx.x & 63;
    int quad = lane >> 4, colL = lane & 15;
    int r0 = row0 + wv * 16;
    h8v afr[KS];
    #pragma unroll
    for (int ks = 0; ks < KS; ++ks)
        afr[ks] = *(const h8v*)(xs + (wv * 16 + colL) * LK + ks * 32 + quad * 8);
    const h8v* bp = (const h8v*)Wp;
    #pragma unroll
    for (int t = 0; t <= NT; ++t) {
        v4f acc = {};
        #pragma unroll
        for (int ks = 0; ks < KS; ++ks) {
            h8v bfr = bp[(size_t)(t * KS + ks) * 64 + lane];
            acc = __builtin_amdgcn_mfma_f32_16x16x32_f16(afr[ks], bfr, acc, 0, 0, 0);
        }
        if (t < NT) {
            int n0 = t * 16;
            int col = n0 + colL;
            int sl = n0 / SLICE;
            int so = col % SLICE;
            _Float16* op = outh + (size_t)sl * N_NODES * SLICE + so;
            #pragma unroll
            for (int reg = 0; reg < 4; ++reg) {
                int row = r0 + quad * 4 + reg;
                if (row < N_NODES) op[(size_t)row * SLICE] = (_Float16)acc[reg];
            }
        } else if (colL < 8) {
            int hd = colL & 3;
            float* sp = (colL < 4) ? ssrc : sdst;
            #pragma unroll
            for (int reg = 0; reg < 4; ++reg) {
                int row = r0 + quad * 4 + reg;
                if (row < N_NODES) sp[row * NH + hd] = acc[reg];
            }
        }
    }
}

// ---------------- normalized softmax weights -> per-head PLANES ----------------
__global__ __launch_bounds__(256) void alpha_k(const float* __restrict__ ssrc,
                                               const float* __restrict__ sdst,
                                               const int* __restrict__ row_ptr,
                                               const int* __restrict__ col,
                                               float* __restrict__ alpha) {
    int wv = threadIdx.x >> 6, lane = threadIdx.x & 63;
    int v = blockIdx.x * 4 + wv;
    if (v >= N_NODES) return;
    int hd = lane >> 4, lg = lane & 15;
    int beg = row_ptr[v], cnt = row_ptr[v + 1] - beg;
    float sdv = sdst[v * NH + hd];
    float* pl = alpha + (size_t)hd * E_TOT + beg;

    if (cnt <= 128) {
        float er[8];
        float m = -FLT_MAX;
        #pragma unroll
        for (int i = 0; i < 8; ++i) {
            int j = lg + i * 16;
            if (j < cnt) {
                int u = col[beg + j];
                float e = ssrc[u * NH + hd] + sdv;
                e = (e > 0.f) ? e : 0.2f * e;
                er[i] = e;
                m = fmaxf(m, e);
            }
        }
        #pragma unroll
        for (int off = 1; off < 16; off <<= 1) m = fmaxf(m, __shfl_xor(m, off));
        float den = 0.f;
        #pragma unroll
        for (int i = 0; i < 8; ++i) {
            int j = lg + i * 16;
            if (j < cnt) { float w = __expf(er[i] - m); er[i] = w; den += w; }
        }
        #pragma unroll
        for (int off = 1; off < 16; off <<= 1) den += __shfl_xor(den, off);
        float inv = 1.f / (den + 1e-16f);
        #pragma unroll
        for (int i = 0; i < 8; ++i) {
            int j = lg + i * 16;
            if (j < cnt) pl[j] = er[i] * inv;
        }
    } else {
        float m = -FLT_MAX;
        for (int j = lg; j < cnt; j += 16) {
            int u = col[beg + j];
            float e = ssrc[u * NH + hd] + sdv;
            e = (e > 0.f) ? e : 0.2f * e;
            m = fmaxf(m, e);
        }
        #pragma unroll
        for (int off = 1; off < 16; off <<= 1) m = fmaxf(m, __shfl_xor(m, off));
        float den = 0.f;
        for (int j = lg; j < cnt; j += 16) {
            int u = col[beg + j];
            float e = ssrc[u * NH + hd] + sdv;
            e = (e > 0.f) ? e : 0.2f * e;
            den += __expf(e - m);
        }
        #pragma unroll
        for (int off = 1; off < 16; off <<= 1) den += __shfl_xor(den, off);
        float inv = 1.f / (den + 1e-16f);
        for (int j = lg; j < cnt; j += 16) {
            int u = col[beg + j];
            float e = ssrc[u * NH + hd] + sdv;
            e = (e > 0.f) ? e : 0.2f * e;
            pl[j] = __expf(e - m) * inv;
        }
    }
}

// ---------------- XCD-sharded aggregation v4 ----------------
// (col, alpha) packed as int2 in LDS (one b64 read per edge); gathers use a
// wave-uniform base + 32-bit offset (SADDR form) to cut address VALU.
template<int HFo, int SLICE, int LPN>
__global__ __launch_bounds__(256) void agg4_k(const _Float16* __restrict__ hh,
                                              const float* __restrict__ alpha,
                                              const int* __restrict__ row_ptr,
                                              const int* __restrict__ col,
                                              const float* __restrict__ bias,
                                              _Float16* __restrict__ outH) {
    constexpr int Fo   = HFo / NH;
    constexpr int NPW  = 64 / LPN;
    constexpr int NPB  = 4 * NPW;
    constexpr int CAPW = NPW * 32;
    __shared__ int2 prS[4][CAPW];
    int s = blockIdx.x & 7;
    int g = blockIdx.x >> 3;
    int wv = threadIdx.x >> 6, lane = threadIdx.x & 63;
    int sub = lane / LPN, lq = lane % LPN;
    int vFirst = g * NPB + wv * NPW;
    if (vFirst >= N_NODES) return;
    int vCount = min(NPW, N_NODES - vFirst);
    int hd = (s * SLICE) / Fo;
    const float* ap = alpha + (size_t)hd * E_TOT;
    int begW = row_ptr[vFirst];
    int endW = row_ptr[vFirst + vCount];
    int len = endW - begW;
    bool active = sub < vCount;
    int v = vFirst + sub;
    int beg = 0, cnt = 0;
    if (active) { beg = row_ptr[v]; cnt = row_ptr[v + 1] - beg; }
    const _Float16* base = hh + (size_t)s * N_NODES * SLICE;  // wave-uniform
    unsigned fo = (unsigned)(lq * 8);
    float acc[8] = {};

    if (len <= CAPW) {
        for (int t = lane; t < len; t += 64)
            prS[wv][t] = make_int2(col[begW + t], __float_as_int(ap[begW + t]));
        __builtin_amdgcn_wave_barrier();
        int off = beg - begW;
        int j = 0;
        for (; j + 8 <= cnt; j += 8) {
            int u[8]; float w[8]; h8v hv[8];
            #pragma unroll
            for (int i = 0; i < 8; ++i) {
                int2 q = prS[wv][off + j + i];
                u[i] = q.x; w[i] = __int_as_float(q.y);
            }
            #pragma unroll
            for (int i = 0; i < 8; ++i)
                hv[i] = *(const h8v*)(base + ((unsigned)(u[i] * SLICE) + fo));
            #pragma unroll
            for (int i = 0; i < 8; ++i)
                #pragma unroll
                for (int c = 0; c < 8; ++c) acc[c] += w[i] * (float)hv[i][c];
        }
        for (; j < cnt; ++j) {
            int2 q = prS[wv][off + j];
            float w = __int_as_float(q.y);
            h8v hv = *(const h8v*)(base + ((unsigned)(q.x * SLICE) + fo));
            #pragma unroll
            for (int c = 0; c < 8; ++c) acc[c] += w * (float)hv[c];
        }
    } else {
        // direct-global fallback (span overflow — practically never)
        const int*   cp = col + beg;
        const float* app = ap + beg;
        for (int j = 0; j < cnt; ++j) {
            int u = cp[j];
            float w = app[j];
            h8v hv = *(const h8v*)(base + ((unsigned)(u * SLICE) + fo));
            #pragma unroll
            for (int c = 0; c < 8; ++c) acc[c] += w * (float)hv[c];
        }
    }
    if (active) {
        int f0 = s * SLICE + lq * 8;
        h8v res;
        #pragma unroll
        for (int c = 0; c < 8; ++c) res[c] = (_Float16)fmaxf(acc[c] + bias[f0 + c], 0.f);
        *(h8v*)(outH + (size_t)v * HFo + f0) = res;
    }
}

// ---------------- pooling (fp16 input; batch sorted -> run-length pre-agg) ----------------
__global__ void pool_k(const _Float16* __restrict__ h, const int* __restrict__ batch,
                       float* __restrict__ gsum, float* __restrict__ gmax) {
    int f = threadIdx.x;  // 256
    int n0 = blockIdx.x * 32;
    int nend = min(n0 + 32, N_NODES);
    int cur = -1;
    float sa = 0.f, ma = 0.f;
    for (int n = n0; n < nend; ++n) {
        int g = batch[n];
        float val = (float)h[(size_t)n * 256 + f];
        if (g != cur) {
            if (cur >= 0) {
                atomicAdd(&gsum[cur * 256 + f], sa);
                atomicMax((int*)&gmax[cur * 256 + f], __float_as_int(ma));
            }
            cur = g; sa = 0.f; ma = 0.f;
        }
        sa += val;
        ma = fmaxf(ma, val);
    }
    if (cur >= 0) {
        atomicAdd(&gsum[cur * 256 + f], sa);
        atomicMax((int*)&gmax[cur * 256 + f], __float_as_int(ma));
    }
}

__global__ void gcnt_k(const int* __restrict__ batch, int* __restrict__ gcnt) {
    int g = threadIdx.x;  // 128 threads
    if (g >= NG) return;
    int lo = 0, hi = N_NODES;
    while (lo < hi) { int mid = (lo + hi) >> 1; if (batch[mid] < g) lo = mid + 1; else hi = mid; }
    int b0 = lo;
    lo = 0; hi = N_NODES;
    while (lo < hi) { int mid = (lo + hi) >> 1; if (batch[mid] < g + 1) lo = mid + 1; else hi = mid; }
    gcnt[g] = lo - b0;
}

__global__ void readout_k(const float* __restrict__ gsum, const float* __restrict__ gmax,
                          const int* __restrict__ gcnt, const float* __restrict__ Wout,
                          const float* __restrict__ bout, float* __restrict__ out) {
    int g = blockIdx.x, lane = threadIdx.x;
    float inv = 1.f / fmaxf((float)gcnt[g], 1.f);
    float acc[10];
    #pragma unroll
    for (int j = 0; j < 10; ++j) acc[j] = 0.f;
    for (int f = lane; f < 512; f += 64) {
        float p = (f < 256) ? gsum[g * 256 + f] * inv : gmax[g * 256 + (f - 256)];
        #pragma unroll
        for (int j = 0; j < 10; ++j) acc[j] += p * Wout[f * 10 + j];
    }
    #pragma unroll
    for (int j = 0; j < 10; ++j) {
        float a = acc[j];
        #pragma unroll
        for (int off = 32; off; off >>= 1) a += __shfl_xor(a, off);
        if (lane == 0) out[g * 10 + j] = a + bout[j];
    }
}

extern "C" void kernel_launch(void* const* d_in, const int* in_sizes, int n_in,
                              void* d_out, int out_size, void* d_ws, size_t ws_size,
                              hipStream_t stream) {
    const float* x    = (const float*)d_in[0];
    const int*   ei   = (const int*)d_in[1];
    const int*   batch= (const int*)d_in[2];
    const float* W0   = (const float*)d_in[3];
    const float* as0  = (const float*)d_in[4];
    const float* ad0  = (const float*)d_in[5];
    const float* b0   = (const float*)d_in[6];
    const float* W1   = (const float*)d_in[7];
    const float* as1  = (const float*)d_in[8];
    const float* ad1  = (const float*)d_in[9];
    const float* b1   = (const float*)d_in[10];
    const float* W2   = (const float*)d_in[11];
    const float* as2  = (const float*)d_in[12];
    const float* ad2  = (const float*)d_in[13];
    const float* b2   = (const float*)d_in[14];
    const float* Wout = (const float*)d_in[15];
    const float* bout = (const float*)d_in[16];
    float* out = (float*)d_out;

    char* ws = (char*)d_ws;
    size_t o = 0;
    auto take = [&](size_t bytes) { size_t r = o; o += (bytes + 255) & ~(size_t)255; return r; };
    size_t cnt_o  = take((size_t)N_NODES * 4);
    size_t gsum_o = take((size_t)NG * 256 * 4);
    size_t gmax_o = take((size_t)NG * 256 * 4);
    size_t gcnt_o = take((size_t)NG * 4);
    size_t zero_bytes = o;
    size_t rp_o   = take((size_t)(N_NODES + 1) * 4);
    size_t cur_o  = take((size_t)N_NODES * 4);
    size_t bsum_o = take((size_t)64 * 4);
    size_t col_o  = take((size_t)E_TOT * 4);
    size_t ssrc_o = take((size_t)N_NODES * NH * 4);
    size_t sdst_o = take((size_t)N_NODES * NH * 4);
    size_t alp_o  = take((size_t)NH * E_TOT * 4);      // per-head alpha planes
    size_t hh_o   = take((size_t)N_NODES * 256 * 2);   // fp16 h slice-major (gather)
    size_t bufH_o = take((size_t)N_NODES * 256 * 2);   // fp16 h row-major (gemm/pool in)
    size_t wp0_o  = take((size_t)(8 + 1) * 4 * 64 * 8 * 2);   // packed W + score tile
    size_t wp1_o  = take((size_t)(16 + 1) * 4 * 64 * 8 * 2);
    size_t wp2_o  = take((size_t)(16 + 1) * 8 * 64 * 8 * 2);

    int*      cnt    = (int*)(ws + cnt_o);
    float*    gsum   = (float*)(ws + gsum_o);
    float*    gmax   = (float*)(ws + gmax_o);
    int*      gcnt   = (int*)(ws + gcnt_o);
    int*      row_ptr= (int*)(ws + rp_o);
    int*      cursor = (int*)(ws + cur_o);
    int*      bsum   = (int*)(ws + bsum_o);
    int*      col    = (int*)(ws + col_o);
    float*    ssrc   = (float*)(ws + ssrc_o);
    float*    sdst   = (float*)(ws + sdst_o);
    float*    alpha  = (float*)(ws + alp_o);
    _Float16* hH     = (_Float16*)(ws + hh_o);
    _Float16* bufH   = (_Float16*)(ws + bufH_o);
    _Float16* Wp0    = (_Float16*)(ws + wp0_o);
    _Float16* Wp1    = (_Float16*)(ws + wp1_o);
    _Float16* Wp2    = (_Float16*)(ws + wp2_o);

    (void)hipMemsetAsync(ws, 0, zero_bytes, stream);

    count_dst_k<<<(E_TOT + 255) / 256, 256, 0, stream>>>(ei, cnt);
    scan_sums_k<<<64, 256, 0, stream>>>(cnt, bsum);
    scan_off_k<<<1, 64, 0, stream>>>(bsum, row_ptr);
    scan_write_k<<<64, 256, 0, stream>>>(cnt, bsum, row_ptr, cursor);
    fill_k<<<(E_TOT + 255) / 256, 256, 0, stream>>>(ei, cursor, col);

    // weight packing + score-tile folds (tiny)
    pack_w_k<128, 128><<<8, 256, 0, stream>>>(W0, Wp0);
    pack_w_k<128, 256><<<16, 256, 0, stream>>>(W1, Wp1);
    pack_w_k<256, 256><<<32, 256, 0, stream>>>(W2, Wp2);
    pack_a_k<128, 128><<<1, 256, 0, stream>>>(W0, as0, ad0, Wp0);
    pack_a_k<128, 256><<<1, 256, 0, stream>>>(W1, as1, ad1, Wp1);
    pack_a_k<256, 256><<<2, 256, 0, stream>>>(W2, as2, ad2, Wp2);

    int gemm_grid  = (N_NODES + 63) / 64;
    int alpha_grid = (N_NODES + 3) / 4;
    int agg128_grid = 8 * ((N_NODES + 127) / 128);
    int agg256_grid = 8 * ((N_NODES + 63) / 64);

    // layer 0: 128 -> H4*Fo32 (128)
    gemm_k<128, 128, float><<<gemm_grid, 256, 0, stream>>>(x, Wp0, hH, ssrc, sdst);
    alpha_k<<<alpha_grid, 256, 0, stream>>>(ssrc, sdst, row_ptr, col, alpha);
    agg4_k<128, 16, 2><<<agg128_grid, 256, 0, stream>>>(hH, alpha, row_ptr, col, b0, bufH);

    // layer 1: 128 -> H4*Fo64 (256)
    gemm_k<128, 256, _Float16><<<gemm_grid, 256, 0, stream>>>(bufH, Wp1, hH, ssrc, sdst);
    alpha_k<<<alpha_grid, 256, 0, stream>>>(ssrc, sdst, row_ptr, col, alpha);
    agg4_k<256, 32, 4><<<agg256_grid, 256, 0, stream>>>(hH, alpha, row_ptr, col, b1, bufH);

    // layer 2: 256 -> H4*Fo64 (256)
    gemm_k<256, 256, _Float16><<<gemm_grid, 256, 0, stream>>>(bufH, Wp2, hH, ssrc, sdst);
    alpha_k<<<alpha_grid, 256, 0, stream>>>(ssrc, sdst, row_ptr, col, alpha);
    agg4_k<256, 32, 4><<<agg256_grid, 256, 0, stream>>>(hH, alpha, row_ptr, col, b2, bufH);

    // pooling + readout
    pool_k<<<(N_NODES + 31) / 32, 256, 0, stream>>>(bufH, batch, gsum, gmax);
    gcnt_k<<<1, 128, 0, stream>>>(batch, gcnt);
    readout_k<<<NG, 64, 0, stream>>>(gsum, gmax, gcnt, Wout, bout, out);
}

// Round 17
// 517.178 us; speedup vs baseline: 1.3490x; 1.0042x over previous
//
#include <hip/hip_runtime.h>
#include <cfloat>

#define N_NODES 50000
#define N_EDGES 800000
#define E_TOT   850000
#define NG      128
#define NH      4
#define CHUNK   782   // ceil(N_NODES/64) for the 64-block scan

typedef float f4 __attribute__((ext_vector_type(4)));
typedef float v4f __attribute__((ext_vector_type(4)));
typedef _Float16 h8v __attribute__((ext_vector_type(8)));

// ---------------- CSR build (by destination) ----------------
__global__ void count_dst_k(const int* __restrict__ ei, int* __restrict__ cnt) {
    int e = blockIdx.x * blockDim.x + threadIdx.x;
    if (e >= E_TOT) return;
    int d = (e < N_EDGES) ? ei[N_EDGES + e] : (e - N_EDGES);
    atomicAdd(&cnt[d], 1);
}

__global__ void scan_sums_k(const int* __restrict__ cnt, int* __restrict__ bsum) {
    int b = blockIdx.x;
    int start = b * CHUNK, end2 = min(start + CHUNK, N_NODES);
    int lane = threadIdx.x & 63, wv = threadIdx.x >> 6;
    int s = 0;
    for (int i = start + threadIdx.x; i < end2; i += 256) s += cnt[i];
    #pragma unroll
    for (int off = 32; off; off >>= 1) s += __shfl_xor(s, off);
    __shared__ int ws[4];
    if (lane == 0) ws[wv] = s;
    __syncthreads();
    if (threadIdx.x == 0) bsum[b] = ws[0] + ws[1] + ws[2] + ws[3];
}

__global__ void scan_off_k(int* __restrict__ bsum, int* __restrict__ row_ptr) {
    int lane = threadIdx.x;  // 64 threads
    int v = bsum[lane];
    int s = v;
    #pragma unroll
    for (int off = 1; off < 64; off <<= 1) {
        int t = __shfl_up(s, off);
        if (lane >= off) s += t;
    }
    bsum[lane] = s - v;  // exclusive
    if (lane == 63) row_ptr[N_NODES] = s;
}

__global__ void scan_write_k(const int* __restrict__ cnt, const int* __restrict__ bsum,
                             int* __restrict__ row_ptr, int* __restrict__ cursor) {
    int b = blockIdx.x;
    int start = b * CHUNK, end2 = min(start + CHUNK, N_NODES);
    __shared__ int wsum[4];
    __shared__ int carry_sh;
    int lane = threadIdx.x & 63, wv = threadIdx.x >> 6;
    if (threadIdx.x == 0) carry_sh = bsum[b];
    __syncthreads();
    for (int base = start; base < end2; base += 256) {
        int i = base + threadIdx.x;
        int v = (i < end2) ? cnt[i] : 0;
        int s = v;
        #pragma unroll
        for (int off = 1; off < 64; off <<= 1) {
            int t = __shfl_up(s, off);
            if (lane >= off) s += t;
        }
        if (lane == 63) wsum[wv] = s;
        __syncthreads();
        int woff = 0;
        #pragma unroll
        for (int k = 0; k < 4; ++k) if (k < wv) woff += wsum[k];
        int carry = carry_sh;
        if (i < end2) { int rp = carry + woff + s - v; row_ptr[i] = rp; cursor[i] = rp; }
        __syncthreads();
        if (threadIdx.x == 0) carry_sh = carry + wsum[0] + wsum[1] + wsum[2] + wsum[3];
        __syncthreads();
    }
}

// direct scatter (write-sector-bound); nt store to dodge L2 line bounce
__global__ void fill_k(const int* __restrict__ ei, int* __restrict__ cursor,
                       int* __restrict__ col) {
    int e = blockIdx.x * blockDim.x + threadIdx.x;
    if (e >= E_TOT) return;
    int s, d;
    if (e < N_EDGES) { s = ei[e]; d = ei[N_EDGES + e]; }
    else { s = e - N_EDGES; d = s; }
    int slot = atomicAdd(&cursor[d], 1);
    __builtin_nontemporal_store(s, &col[slot]);
}

// ---------------- pack W (fp32 KxNOUT) into MFMA B-fragment order, fp16 ----------------
template<int K, int NOUT>
__global__ void pack_w_k(const float* __restrict__ W, _Float16* __restrict__ Wp) {
    constexpr int total = (NOUT / 16) * (K / 32) * 64;
    int t = blockIdx.x * blockDim.x + threadIdx.x;
    if (t >= total) return;
    int lane = t & 63;
    int rest = t >> 6;
    int ks = rest % (K / 32);
    int n  = rest / (K / 32);
    int colW = n * 16 + (lane & 15);
    int krow = ks * 32 + (lane >> 4) * 8;
    h8v v;
    #pragma unroll
    for (int j = 0; j < 8; ++j) v[j] = (_Float16)W[(size_t)(krow + j) * NOUT + colW];
    *(h8v*)(Wp + (size_t)t * 8) = v;
}

// fold a_src/a_dst into the extra score tile (tile NT)
template<int K, int NOUT>
__global__ void pack_a_k(const float* __restrict__ W, const float* __restrict__ asrc,
                         const float* __restrict__ adst, _Float16* __restrict__ Wp) {
    constexpr int KS = K / 32;
    constexpr int NT = NOUT / 16;
    constexpr int Fo = NOUT / NH;
    int t = blockIdx.x * blockDim.x + threadIdx.x;
    if (t >= KS * 64) return;
    int ks = t >> 6, lane = t & 63;
    int colL = lane & 15;
    int krow = ks * 32 + ((lane >> 4) & 3) * 8;
    h8v v = {};
    if (colL < 8) {
        int hd = colL & 3;
        const float* av = (colL < 4) ? asrc : adst;
        #pragma unroll
        for (int j = 0; j < 8; ++j) {
            float s = 0.f;
            const float* wr = W + (size_t)(krow + j) * NOUT + hd * Fo;
            for (int f = 0; f < Fo; ++f) s += wr[f] * av[hd * Fo + f];
            v[j] = (_Float16)s;
        }
    }
    *(h8v*)(Wp + (size_t)((NT * KS + ks) * 64 + lane) * 8) = v;
}

// ---------------- MFMA GEMM; h slice-major fp16 + scores via folded tile ----------------
template<int K, int NOUT, typename XT>
__global__ __launch_bounds__(256) void gemm_k(const XT* __restrict__ x,
                                              const _Float16* __restrict__ Wp,
                                              _Float16* __restrict__ outh,
                                              float* __restrict__ ssrc,
                                              float* __restrict__ sdst) {
    constexpr int SLICE = NOUT / 8;
    constexpr int KS  = K / 32;
    constexpr int NT  = NOUT / 16;
    constexpr int LK  = K + 8;
    __shared__ __align__(16) _Float16 xs[64 * LK];
    int row0 = blockIdx.x * 64;
    for (int seg = threadIdx.x; seg < 64 * K / 8; seg += 256) {
        int r = seg / (K / 8);
        int c = (seg % (K / 8)) * 8;
        h8v v = {};
        if (row0 + r < N_NODES) {
            if constexpr (sizeof(XT) == 2) {
                v = *(const h8v*)((const _Float16*)x + (size_t)(row0 + r) * K + c);
            } else {
                const float* xp = (const float*)x + (size_t)(row0 + r) * K + c;
                float4 a = *(const float4*)xp;
                float4 b = *(const float4*)(xp + 4);
                v[0] = (_Float16)a.x; v[1] = (_Float16)a.y;
                v[2] = (_Float16)a.z; v[3] = (_Float16)a.w;
                v[4] = (_Float16)b.x; v[5] = (_Float16)b.y;
                v[6] = (_Float16)b.z; v[7] = (_Float16)b.w;
            }
        }
        *(h8v*)(xs + r * LK + c) = v;
    }
    __syncthreads();
    int wv = threadIdx.x >> 6, lane = threadIdx.x & 63;
    int quad = lane >> 4, colL = lane & 15;
    int r0 = row0 + wv * 16;
    h8v afr[KS];
    #pragma unroll
    for (int ks = 0; ks < KS; ++ks)
        afr[ks] = *(const h8v*)(xs + (wv * 16 + colL) * LK + ks * 32 + quad * 8);
    const h8v* bp = (const h8v*)Wp;
    #pragma unroll
    for (int t = 0; t <= NT; ++t) {
        v4f acc = {};
        #pragma unroll
        for (int ks = 0; ks < KS; ++ks) {
            h8v bfr = bp[(size_t)(t * KS + ks) * 64 + lane];
            acc = __builtin_amdgcn_mfma_f32_16x16x32_f16(afr[ks], bfr, acc, 0, 0, 0);
        }
        if (t < NT) {
            int n0 = t * 16;
            int col = n0 + colL;
            int sl = n0 / SLICE;
            int so = col % SLICE;
            _Float16* op = outh + (size_t)sl * N_NODES * SLICE + so;
            #pragma unroll
            for (int reg = 0; reg < 4; ++reg) {
                int row = r0 + quad * 4 + reg;
                if (row < N_NODES) op[(size_t)row * SLICE] = (_Float16)acc[reg];
            }
        } else if (colL < 8) {
            int hd = colL & 3;
            float* sp = (colL < 4) ? ssrc : sdst;
            #pragma unroll
            for (int reg = 0; reg < 4; ++reg) {
                int row = r0 + quad * 4 + reg;
                if (row < N_NODES) sp[row * NH + hd] = acc[reg];
            }
        }
    }
}

// ---------------- head-vectorized alpha: 16-lane group per node, all 4 heads ----------------
// alpha planes: alpha[hd*E_TOT + e]
__global__ __launch_bounds__(256) void alpha2_k(const float* __restrict__ ssrc,
                                                const float* __restrict__ sdst,
                                                const int* __restrict__ row_ptr,
                                                const int* __restrict__ col,
                                                float* __restrict__ alpha) {
    int wv = threadIdx.x >> 6, lane = threadIdx.x & 63;
    int grp = lane >> 4, lg = lane & 15;
    int v = blockIdx.x * 16 + wv * 4 + grp;
    if (v >= N_NODES) return;
    int beg = row_ptr[v], cnt = row_ptr[v + 1] - beg;
    f4 sdv = *(const f4*)(sdst + v * NH);
    float* pl0 = alpha + beg;
    float* pl1 = alpha + (size_t)E_TOT + beg;
    float* pl2 = alpha + (size_t)2 * E_TOT + beg;
    float* pl3 = alpha + (size_t)3 * E_TOT + beg;

    if (cnt <= 64) {
        f4 er[4];
        f4 m = {-FLT_MAX, -FLT_MAX, -FLT_MAX, -FLT_MAX};
        #pragma unroll
        for (int i = 0; i < 4; ++i) {
            int j = lg + i * 16;
            if (j < cnt) {
                int u = col[beg + j];
                f4 e = *(const f4*)(ssrc + u * NH) + sdv;
                #pragma unroll
                for (int c = 0; c < 4; ++c) e[c] = (e[c] > 0.f) ? e[c] : 0.2f * e[c];
                er[i] = e;
                #pragma unroll
                for (int c = 0; c < 4; ++c) m[c] = fmaxf(m[c], e[c]);
            }
        }
        #pragma unroll
        for (int off = 1; off < 16; off <<= 1)
            #pragma unroll
            for (int c = 0; c < 4; ++c) m[c] = fmaxf(m[c], __shfl_xor(m[c], off));
        f4 den = {};
        #pragma unroll
        for (int i = 0; i < 4; ++i) {
            int j = lg + i * 16;
            if (j < cnt) {
                f4 w;
                #pragma unroll
                for (int c = 0; c < 4; ++c) w[c] = __expf(er[i][c] - m[c]);
                er[i] = w;
                den += w;
            }
        }
        #pragma unroll
        for (int off = 1; off < 16; off <<= 1)
            #pragma unroll
            for (int c = 0; c < 4; ++c) den[c] += __shfl_xor(den[c], off);
        f4 inv;
        #pragma unroll
        for (int c = 0; c < 4; ++c) inv[c] = 1.f / (den[c] + 1e-16f);
        #pragma unroll
        for (int i = 0; i < 4; ++i) {
            int j = lg + i * 16;
            if (j < cnt) {
                pl0[j] = er[i][0] * inv[0];
                pl1[j] = er[i][1] * inv[1];
                pl2[j] = er[i][2] * inv[2];
                pl3[j] = er[i][3] * inv[3];
            }
        }
    } else {
        // streaming 3-pass (practically never taken)
        f4 m = {-FLT_MAX, -FLT_MAX, -FLT_MAX, -FLT_MAX};
        for (int j = lg; j < cnt; j += 16) {
            int u = col[beg + j];
            f4 e = *(const f4*)(ssrc + u * NH) + sdv;
            #pragma unroll
            for (int c = 0; c < 4; ++c) {
                e[c] = (e[c] > 0.f) ? e[c] : 0.2f * e[c];
                m[c] = fmaxf(m[c], e[c]);
            }
        }
        #pragma unroll
        for (int off = 1; off < 16; off <<= 1)
            #pragma unroll
            for (int c = 0; c < 4; ++c) m[c] = fmaxf(m[c], __shfl_xor(m[c], off));
        f4 den = {};
        for (int j = lg; j < cnt; j += 16) {
            int u = col[beg + j];
            f4 e = *(const f4*)(ssrc + u * NH) + sdv;
            #pragma unroll
            for (int c = 0; c < 4; ++c) {
                e[c] = (e[c] > 0.f) ? e[c] : 0.2f * e[c];
                den[c] += __expf(e[c] - m[c]);
            }
        }
        #pragma unroll
        for (int off = 1; off < 16; off <<= 1)
            #pragma unroll
            for (int c = 0; c < 4; ++c) den[c] += __shfl_xor(den[c], off);
        f4 inv;
        #pragma unroll
        for (int c = 0; c < 4; ++c) inv[c] = 1.f / (den[c] + 1e-16f);
        for (int j = lg; j < cnt; j += 16) {
            int u = col[beg + j];
            f4 e = *(const f4*)(ssrc + u * NH) + sdv;
            #pragma unroll
            for (int c = 0; c < 4; ++c) e[c] = (e[c] > 0.f) ? e[c] : 0.2f * e[c];
            pl0[j] = __expf(e[0] - m[0]) * inv[0];
            pl1[j] = __expf(e[1] - m[1]) * inv[1];
            pl2[j] = __expf(e[2] - m[2]) * inv[2];
            pl3[j] = __expf(e[3] - m[3]) * inv[3];
        }
    }
}

// ---------------- XCD-sharded aggregation v4 ----------------
template<int HFo, int SLICE, int LPN>
__global__ __launch_bounds__(256) void agg4_k(const _Float16* __restrict__ hh,
                                              const float* __restrict__ alpha,
                                              const int* __restrict__ row_ptr,
                                              const int* __restrict__ col,
                                              const float* __restrict__ bias,
                                              _Float16* __restrict__ outH) {
    constexpr int Fo   = HFo / NH;
    constexpr int NPW  = 64 / LPN;
    constexpr int NPB  = 4 * NPW;
    constexpr int CAPW = NPW * 32;
    __shared__ int2 prS[4][CAPW];
    int s = blockIdx.x & 7;
    int g = blockIdx.x >> 3;
    int wv = threadIdx.x >> 6, lane = threadIdx.x & 63;
    int sub = lane / LPN, lq = lane % LPN;
    int vFirst = g * NPB + wv * NPW;
    if (vFirst >= N_NODES) return;
    int vCount = min(NPW, N_NODES - vFirst);
    int hd = (s * SLICE) / Fo;
    const float* ap = alpha + (size_t)hd * E_TOT;
    int begW = row_ptr[vFirst];
    int endW = row_ptr[vFirst + vCount];
    int len = endW - begW;
    bool active = sub < vCount;
    int v = vFirst + sub;
    int beg = 0, cnt = 0;
    if (active) { beg = row_ptr[v]; cnt = row_ptr[v + 1] - beg; }
    const _Float16* base = hh + (size_t)s * N_NODES * SLICE;  // wave-uniform
    unsigned fo = (unsigned)(lq * 8);
    float acc[8] = {};

    if (len <= CAPW) {
        for (int t = lane; t < len; t += 64)
            prS[wv][t] = make_int2(col[begW + t], __float_as_int(ap[begW + t]));
        __builtin_amdgcn_wave_barrier();
        int off = beg - begW;
        int j = 0;
        for (; j + 8 <= cnt; j += 8) {
            int u[8]; float w[8]; h8v hv[8];
            #pragma unroll
            for (int i = 0; i < 8; ++i) {
                int2 q = prS[wv][off + j + i];
                u[i] = q.x; w[i] = __int_as_float(q.y);
            }
            #pragma unroll
            for (int i = 0; i < 8; ++i)
                hv[i] = *(const h8v*)(base + ((unsigned)(u[i] * SLICE) + fo));
            #pragma unroll
            for (int i = 0; i < 8; ++i)
                #pragma unroll
                for (int c = 0; c < 8; ++c) acc[c] += w[i] * (float)hv[i][c];
        }
        for (; j < cnt; ++j) {
            int2 q = prS[wv][off + j];
            float w = __int_as_float(q.y);
            h8v hv = *(const h8v*)(base + ((unsigned)(q.x * SLICE) + fo));
            #pragma unroll
            for (int c = 0; c < 8; ++c) acc[c] += w * (float)hv[c];
        }
    } else {
        const int*   cp = col + beg;
        const float* app = ap + beg;
        for (int j = 0; j < cnt; ++j) {
            int u = cp[j];
            float w = app[j];
            h8v hv = *(const h8v*)(base + ((unsigned)(u * SLICE) + fo));
            #pragma unroll
            for (int c = 0; c < 8; ++c) acc[c] += w * (float)hv[c];
        }
    }
    if (active) {
        int f0 = s * SLICE + lq * 8;
        h8v res;
        #pragma unroll
        for (int c = 0; c < 8; ++c) res[c] = (_Float16)fmaxf(acc[c] + bias[f0 + c], 0.f);
        *(h8v*)(outH + (size_t)v * HFo + f0) = res;
    }
}

// ---------------- pooling (fp16 input; batch sorted -> run-length pre-agg) ----------------
__global__ void pool_k(const _Float16* __restrict__ h, const int* __restrict__ batch,
                       float* __restrict__ gsum, float* __restrict__ gmax) {
    int f = threadIdx.x;  // 256
    int n0 = blockIdx.x * 32;
    int nend = min(n0 + 32, N_NODES);
    int cur = -1;
    float sa = 0.f, ma = 0.f;
    for (int n = n0; n < nend; ++n) {
        int g = batch[n];
        float val = (float)h[(size_t)n * 256 + f];
        if (g != cur) {
            if (cur >= 0) {
                atomicAdd(&gsum[cur * 256 + f], sa);
                atomicMax((int*)&gmax[cur * 256 + f], __float_as_int(ma));
            }
            cur = g; sa = 0.f; ma = 0.f;
        }
        sa += val;
        ma = fmaxf(ma, val);
    }
    if (cur >= 0) {
        atomicAdd(&gsum[cur * 256 + f], sa);
        atomicMax((int*)&gmax[cur * 256 + f], __float_as_int(ma));
    }
}

__global__ void gcnt_k(const int* __restrict__ batch, int* __restrict__ gcnt) {
    int g = threadIdx.x;  // 128 threads
    if (g >= NG) return;
    int lo = 0, hi = N_NODES;
    while (lo < hi) { int mid = (lo + hi) >> 1; if (batch[mid] < g) lo = mid + 1; else hi = mid; }
    int b0 = lo;
    lo = 0; hi = N_NODES;
    while (lo < hi) { int mid = (lo + hi) >> 1; if (batch[mid] < g + 1) lo = mid + 1; else hi = mid; }
    gcnt[g] = lo - b0;
}

__global__ void readout_k(const float* __restrict__ gsum, const float* __restrict__ gmax,
                          const int* __restrict__ gcnt, const float* __restrict__ Wout,
                          const float* __restrict__ bout, float* __restrict__ out) {
    int g = blockIdx.x, lane = threadIdx.x;
    float inv = 1.f / fmaxf((float)gcnt[g], 1.f);
    float acc[10];
    #pragma unroll
    for (int j = 0; j < 10; ++j) acc[j] = 0.f;
    for (int f = lane; f < 512; f += 64) {
        float p = (f < 256) ? gsum[g * 256 + f] * inv : gmax[g * 256 + (f - 256)];
        #pragma unroll
        for (int j = 0; j < 10; ++j) acc[j] += p * Wout[f * 10 + j];
    }
    #pragma unroll
    for (int j = 0; j < 10; ++j) {
        float a = acc[j];
        #pragma unroll
        for (int off = 32; off; off >>= 1) a += __shfl_xor(a, off);
        if (lane == 0) out[g * 10 + j] = a + bout[j];
    }
}

extern "C" void kernel_launch(void* const* d_in, const int* in_sizes, int n_in,
                              void* d_out, int out_size, void* d_ws, size_t ws_size,
                              hipStream_t stream) {
    const float* x    = (const float*)d_in[0];
    const int*   ei   = (const int*)d_in[1];
    const int*   batch= (const int*)d_in[2];
    const float* W0   = (const float*)d_in[3];
    const float* as0  = (const float*)d_in[4];
    const float* ad0  = (const float*)d_in[5];
    const float* b0   = (const float*)d_in[6];
    const float* W1   = (const float*)d_in[7];
    const float* as1  = (const float*)d_in[8];
    const float* ad1  = (const float*)d_in[9];
    const float* b1   = (const float*)d_in[10];
    const float* W2   = (const float*)d_in[11];
    const float* as2  = (const float*)d_in[12];
    const float* ad2  = (const float*)d_in[13];
    const float* b2   = (const float*)d_in[14];
    const float* Wout = (const float*)d_in[15];
    const float* bout = (const float*)d_in[16];
    float* out = (float*)d_out;

    char* ws = (char*)d_ws;
    size_t o = 0;
    auto take = [&](size_t bytes) { size_t r = o; o += (bytes + 255) & ~(size_t)255; return r; };
    size_t cnt_o  = take((size_t)N_NODES * 4);
    size_t gsum_o = take((size_t)NG * 256 * 4);
    size_t gmax_o = take((size_t)NG * 256 * 4);
    size_t gcnt_o = take((size_t)NG * 4);
    size_t zero_bytes = o;
    size_t rp_o   = take((size_t)(N_NODES + 1) * 4);
    size_t cur_o  = take((size_t)N_NODES * 4);
    size_t bsum_o = take((size_t)64 * 4);
    size_t col_o  = take((size_t)E_TOT * 4);
    size_t ssrc_o = take((size_t)N_NODES * NH * 4);
    size_t sdst_o = take((size_t)N_NODES * NH * 4);
    size_t alp_o  = take((size_t)NH * E_TOT * 4);      // per-head alpha planes
    size_t hh_o   = take((size_t)N_NODES * 256 * 2);   // fp16 h slice-major (gather)
    size_t bufH_o = take((size_t)N_NODES * 256 * 2);   // fp16 h row-major (gemm/pool in)
    size_t wp0_o  = take((size_t)(8 + 1) * 4 * 64 * 8 * 2);   // packed W + score tile
    size_t wp1_o  = take((size_t)(16 + 1) * 4 * 64 * 8 * 2);
    size_t wp2_o  = take((size_t)(16 + 1) * 8 * 64 * 8 * 2);

    int*      cnt    = (int*)(ws + cnt_o);
    float*    gsum   = (float*)(ws + gsum_o);
    float*    gmax   = (float*)(ws + gmax_o);
    int*      gcnt   = (int*)(ws + gcnt_o);
    int*      row_ptr= (int*)(ws + rp_o);
    int*      cursor = (int*)(ws + cur_o);
    int*      bsum   = (int*)(ws + bsum_o);
    int*      col    = (int*)(ws + col_o);
    float*    ssrc   = (float*)(ws + ssrc_o);
    float*    sdst   = (float*)(ws + sdst_o);
    float*    alpha  = (float*)(ws + alp_o);
    _Float16* hH     = (_Float16*)(ws + hh_o);
    _Float16* bufH   = (_Float16*)(ws + bufH_o);
    _Float16* Wp0    = (_Float16*)(ws + wp0_o);
    _Float16* Wp1    = (_Float16*)(ws + wp1_o);
    _Float16* Wp2    = (_Float16*)(ws + wp2_o);

    (void)hipMemsetAsync(ws, 0, zero_bytes, stream);

    count_dst_k<<<(E_TOT + 255) / 256, 256, 0, stream>>>(ei, cnt);
    scan_sums_k<<<64, 256, 0, stream>>>(cnt, bsum);
    scan_off_k<<<1, 64, 0, stream>>>(bsum, row_ptr);
    scan_write_k<<<64, 256, 0, stream>>>(cnt, bsum, row_ptr, cursor);
    fill_k<<<(E_TOT + 255) / 256, 256, 0, stream>>>(ei, cursor, col);

    // weight packing + score-tile folds (tiny)
    pack_w_k<128, 128><<<8, 256, 0, stream>>>(W0, Wp0);
    pack_w_k<128, 256><<<16, 256, 0, stream>>>(W1, Wp1);
    pack_w_k<256, 256><<<32, 256, 0, stream>>>(W2, Wp2);
    pack_a_k<128, 128><<<1, 256, 0, stream>>>(W0, as0, ad0, Wp0);
    pack_a_k<128, 256><<<1, 256, 0, stream>>>(W1, as1, ad1, Wp1);
    pack_a_k<256, 256><<<2, 256, 0, stream>>>(W2, as2, ad2, Wp2);

    int gemm_grid  = (N_NODES + 63) / 64;
    int alpha_grid = (N_NODES + 15) / 16;
    int agg128_grid = 8 * ((N_NODES + 127) / 128);
    int agg256_grid = 8 * ((N_NODES + 63) / 64);

    // layer 0: 128 -> H4*Fo32 (128)
    gemm_k<128, 128, float><<<gemm_grid, 256, 0, stream>>>(x, Wp0, hH, ssrc, sdst);
    alpha2_k<<<alpha_grid, 256, 0, stream>>>(ssrc, sdst, row_ptr, col, alpha);
    agg4_k<128, 16, 2><<<agg128_grid, 256, 0, stream>>>(hH, alpha, row_ptr, col, b0, bufH);

    // layer 1: 128 -> H4*Fo64 (256)
    gemm_k<128, 256, _Float16><<<gemm_grid, 256, 0, stream>>>(bufH, Wp1, hH, ssrc, sdst);
    alpha2_k<<<alpha_grid, 256, 0, stream>>>(ssrc, sdst, row_ptr, col, alpha);
    agg4_k<256, 32, 4><<<agg256_grid, 256, 0, stream>>>(hH, alpha, row_ptr, col, b1, bufH);

    // layer 2: 256 -> H4*Fo64 (256)
    gemm_k<256, 256, _Float16><<<gemm_grid, 256, 0, stream>>>(bufH, Wp2, hH, ssrc, sdst);
    alpha2_k<<<alpha_grid, 256, 0, stream>>>(ssrc, sdst, row_ptr, col, alpha);
    agg4_k<256, 32, 4><<<agg256_grid, 256, 0, stream>>>(hH, alpha, row_ptr, col, b2, bufH);

    // pooling + readout
    pool_k<<<(N_NODES + 31) / 32, 256, 0, stream>>>(bufH, batch, gsum, gmax);
    gcnt_k<<<1, 128, 0, stream>>>(batch, gcnt);
    readout_k<<<NG, 64, 0, stream>>>(gsum, gmax, gcnt, Wout, bout, out);
}

// Round 18
// 476.871 us; speedup vs baseline: 1.4631x; 1.0845x over previous
//
#include <hip/hip_runtime.h>
#include <cfloat>

#define N_NODES 50000
#define N_EDGES 800000
#define E_TOT   850000
#define NG      128
#define NH      4
#define CHUNK   782   // ceil(N_NODES/64) for the 64-block scan

typedef float f4 __attribute__((ext_vector_type(4)));
typedef float v4f __attribute__((ext_vector_type(4)));
typedef _Float16 h2v __attribute__((ext_vector_type(2)));
typedef _Float16 h8v __attribute__((ext_vector_type(8)));

// ---------------- CSR build (by destination) ----------------
__global__ void count_dst_k(const int* __restrict__ ei, int* __restrict__ cnt) {
    int e = blockIdx.x * blockDim.x + threadIdx.x;
    if (e >= E_TOT) return;
    int d = (e < N_EDGES) ? ei[N_EDGES + e] : (e - N_EDGES);
    atomicAdd(&cnt[d], 1);
}

__global__ void scan_sums_k(const int* __restrict__ cnt, int* __restrict__ bsum) {
    int b = blockIdx.x;
    int start = b * CHUNK, end2 = min(start + CHUNK, N_NODES);
    int lane = threadIdx.x & 63, wv = threadIdx.x >> 6;
    int s = 0;
    for (int i = start + threadIdx.x; i < end2; i += 256) s += cnt[i];
    #pragma unroll
    for (int off = 32; off; off >>= 1) s += __shfl_xor(s, off);
    __shared__ int ws[4];
    if (lane == 0) ws[wv] = s;
    __syncthreads();
    if (threadIdx.x == 0) bsum[b] = ws[0] + ws[1] + ws[2] + ws[3];
}

__global__ void scan_off_k(int* __restrict__ bsum, int* __restrict__ row_ptr) {
    int lane = threadIdx.x;  // 64 threads
    int v = bsum[lane];
    int s = v;
    #pragma unroll
    for (int off = 1; off < 64; off <<= 1) {
        int t = __shfl_up(s, off);
        if (lane >= off) s += t;
    }
    bsum[lane] = s - v;  // exclusive
    if (lane == 63) row_ptr[N_NODES] = s;
}

__global__ void scan_write_k(const int* __restrict__ cnt, const int* __restrict__ bsum,
                             int* __restrict__ row_ptr, int* __restrict__ cursor) {
    int b = blockIdx.x;
    int start = b * CHUNK, end2 = min(start + CHUNK, N_NODES);
    __shared__ int wsum[4];
    __shared__ int carry_sh;
    int lane = threadIdx.x & 63, wv = threadIdx.x >> 6;
    if (threadIdx.x == 0) carry_sh = bsum[b];
    __syncthreads();
    for (int base = start; base < end2; base += 256) {
        int i = base + threadIdx.x;
        int v = (i < end2) ? cnt[i] : 0;
        int s = v;
        #pragma unroll
        for (int off = 1; off < 64; off <<= 1) {
            int t = __shfl_up(s, off);
            if (lane >= off) s += t;
        }
        if (lane == 63) wsum[wv] = s;
        __syncthreads();
        int woff = 0;
        #pragma unroll
        for (int k = 0; k < 4; ++k) if (k < wv) woff += wsum[k];
        int carry = carry_sh;
        if (i < end2) { int rp = carry + woff + s - v; row_ptr[i] = rp; cursor[i] = rp; }
        __syncthreads();
        if (threadIdx.x == 0) carry_sh = carry + wsum[0] + wsum[1] + wsum[2] + wsum[3];
        __syncthreads();
    }
}

// direct scatter (known-good; write-sector-bound ~55 us)
__global__ void fill_k(const int* __restrict__ ei, int* __restrict__ cursor,
                       int* __restrict__ col) {
    int e = blockIdx.x * blockDim.x + threadIdx.x;
    if (e >= E_TOT) return;
    int s, d;
    if (e < N_EDGES) { s = ei[e]; d = ei[N_EDGES + e]; }
    else { s = e - N_EDGES; d = s; }
    int slot = atomicAdd(&cursor[d], 1);
    col[slot] = s;
}

// ---------------- pack W into MFMA B-fragment order, fp16 (merged) ----------------
template<int K, int NOUT>
__device__ void pack_w_dev(const float* __restrict__ W, _Float16* __restrict__ Wp, int blk) {
    int t = blk * 256 + threadIdx.x;
    if (t >= (NOUT / 16) * (K / 32) * 64) return;
    int lane = t & 63;
    int rest = t >> 6;
    int ks = rest % (K / 32);
    int n  = rest / (K / 32);
    int colW = n * 16 + (lane & 15);
    int krow = ks * 32 + (lane >> 4) * 8;
    h8v v;
    #pragma unroll
    for (int j = 0; j < 8; ++j) v[j] = (_Float16)W[(size_t)(krow + j) * NOUT + colW];
    *(h8v*)(Wp + (size_t)t * 8) = v;
}

__global__ void pack_w_all_k(const float* __restrict__ W0, const float* __restrict__ W1,
                             const float* __restrict__ W2, _Float16* __restrict__ Wp0,
                             _Float16* __restrict__ Wp1, _Float16* __restrict__ Wp2) {
    int b = blockIdx.x;  // 56 blocks: 8 + 16 + 32
    if (b < 8)       pack_w_dev<128, 128>(W0, Wp0, b);
    else if (b < 24) pack_w_dev<128, 256>(W1, Wp1, b - 8);
    else             pack_w_dev<256, 256>(W2, Wp2, b - 24);
}

// fold a_src/a_dst into the extra score tile (tile NT) — merged
template<int K, int NOUT>
__device__ void pack_a_dev(const float* __restrict__ W, const float* __restrict__ asrc,
                           const float* __restrict__ adst, _Float16* __restrict__ Wp, int blk) {
    constexpr int KS = K / 32;
    constexpr int NT = NOUT / 16;
    constexpr int Fo = NOUT / NH;
    int t = blk * 256 + threadIdx.x;
    if (t >= KS * 64) return;
    int ks = t >> 6, lane = t & 63;
    int colL = lane & 15;
    int krow = ks * 32 + ((lane >> 4) & 3) * 8;
    h8v v = {};
    if (colL < 8) {
        int hd = colL & 3;
        const float* av = (colL < 4) ? asrc : adst;
        #pragma unroll
        for (int j = 0; j < 8; ++j) {
            float s = 0.f;
            const float* wr = W + (size_t)(krow + j) * NOUT + hd * Fo;
            for (int f = 0; f < Fo; ++f) s += wr[f] * av[hd * Fo + f];
            v[j] = (_Float16)s;
        }
    }
    *(h8v*)(Wp + (size_t)((NT * KS + ks) * 64 + lane) * 8) = v;
}

__global__ void pack_a_all_k(const float* __restrict__ W0, const float* __restrict__ as0,
                             const float* __restrict__ ad0, _Float16* __restrict__ Wp0,
                             const float* __restrict__ W1, const float* __restrict__ as1,
                             const float* __restrict__ ad1, _Float16* __restrict__ Wp1,
                             const float* __restrict__ W2, const float* __restrict__ as2,
                             const float* __restrict__ ad2, _Float16* __restrict__ Wp2) {
    int b = blockIdx.x;  // 4 blocks: 1 + 1 + 2
    if (b == 0)      pack_a_dev<128, 128>(W0, as0, ad0, Wp0, 0);
    else if (b == 1) pack_a_dev<128, 256>(W1, as1, ad1, Wp1, 0);
    else             pack_a_dev<256, 256>(W2, as2, ad2, Wp2, b - 2);
}

// ---------------- MFMA GEMM, fp32 input (layer 0): LDS-staged, 64 rows ----------------
template<int K, int NOUT>
__global__ __launch_bounds__(256) void gemm_k(const float* __restrict__ x,
                                              const _Float16* __restrict__ Wp,
                                              _Float16* __restrict__ outh,
                                              float* __restrict__ ssrc,
                                              float* __restrict__ sdst) {
    constexpr int SLICE = NOUT / 8;
    constexpr int KS  = K / 32;
    constexpr int NT  = NOUT / 16;
    constexpr int LK  = K + 8;
    __shared__ __align__(16) _Float16 xs[64 * LK];
    int row0 = blockIdx.x * 64;
    for (int seg = threadIdx.x; seg < 64 * K / 8; seg += 256) {
        int r = seg / (K / 8);
        int c = (seg % (K / 8)) * 8;
        h8v v = {};
        if (row0 + r < N_NODES) {
            const float* xp = x + (size_t)(row0 + r) * K + c;
            float4 a = *(const float4*)xp;
            float4 b = *(const float4*)(xp + 4);
            v[0] = (_Float16)a.x; v[1] = (_Float16)a.y;
            v[2] = (_Float16)a.z; v[3] = (_Float16)a.w;
            v[4] = (_Float16)b.x; v[5] = (_Float16)b.y;
            v[6] = (_Float16)b.z; v[7] = (_Float16)b.w;
        }
        *(h8v*)(xs + r * LK + c) = v;
    }
    __syncthreads();
    int wv = threadIdx.x >> 6, lane = threadIdx.x & 63;
    int quad = lane >> 4, colL = lane & 15;
    int r0 = row0 + wv * 16;
    h8v afr[KS];
    #pragma unroll
    for (int ks = 0; ks < KS; ++ks)
        afr[ks] = *(const h8v*)(xs + (wv * 16 + colL) * LK + ks * 32 + quad * 8);
    const h8v* bp = (const h8v*)Wp;
    #pragma unroll
    for (int t = 0; t <= NT; ++t) {
        v4f acc = {};
        #pragma unroll
        for (int ks = 0; ks < KS; ++ks) {
            h8v bfr = bp[(size_t)(t * KS + ks) * 64 + lane];
            acc = __builtin_amdgcn_mfma_f32_16x16x32_f16(afr[ks], bfr, acc, 0, 0, 0);
        }
        if (t < NT) {
            int n0 = t * 16;
            int col = n0 + colL;
            int sl = n0 / SLICE;
            int so = col % SLICE;
            _Float16* op = outh + (size_t)sl * N_NODES * SLICE + so;
            #pragma unroll
            for (int reg = 0; reg < 4; ++reg) {
                int row = r0 + quad * 4 + reg;
                if (row < N_NODES) op[(size_t)row * SLICE] = (_Float16)acc[reg];
            }
        } else if (colL < 8) {
            int hd = colL & 3;
            float* sp = (colL < 4) ? ssrc : sdst;
            #pragma unroll
            for (int reg = 0; reg < 4; ++reg) {
                int row = r0 + quad * 4 + reg;
                if (row < N_NODES) sp[row * NH + hd] = acc[reg];
            }
        }
    }
}

// ---------------- MFMA GEMM, fp16 input (layers 1,2): no LDS, A direct-from-global,
// 128 rows/block = 2 row-tiles per wave sharing each B-fragment load ----------------
template<int K, int NOUT>
__global__ __launch_bounds__(256) void gemm_h_k(const _Float16* __restrict__ x,
                                                const _Float16* __restrict__ Wp,
                                                _Float16* __restrict__ outh,
                                                float* __restrict__ ssrc,
                                                float* __restrict__ sdst) {
    constexpr int SLICE = NOUT / 8;
    constexpr int KS = K / 32;
    constexpr int NT = NOUT / 16;
    int wv = threadIdx.x >> 6, lane = threadIdx.x & 63;
    int quad = lane >> 4, colL = lane & 15;
    int row0 = blockIdx.x * 128;
    int r0a = row0 + wv * 16;
    int r0b = row0 + 64 + wv * 16;
    int rA = min(r0a + colL, N_NODES - 1);
    int rB = min(r0b + colL, N_NODES - 1);
    h8v afrA[KS], afrB[KS];
    #pragma unroll
    for (int ks = 0; ks < KS; ++ks) {
        afrA[ks] = *(const h8v*)(x + (size_t)rA * K + ks * 32 + quad * 8);
        afrB[ks] = *(const h8v*)(x + (size_t)rB * K + ks * 32 + quad * 8);
    }
    const h8v* bp = (const h8v*)Wp;
    #pragma unroll
    for (int t = 0; t <= NT; ++t) {
        v4f accA = {}, accB = {};
        #pragma unroll
        for (int ks = 0; ks < KS; ++ks) {
            h8v bfr = bp[(size_t)(t * KS + ks) * 64 + lane];
            accA = __builtin_amdgcn_mfma_f32_16x16x32_f16(afrA[ks], bfr, accA, 0, 0, 0);
            accB = __builtin_amdgcn_mfma_f32_16x16x32_f16(afrB[ks], bfr, accB, 0, 0, 0);
        }
        if (t < NT) {
            int n0 = t * 16;
            int col = n0 + colL;
            int sl = n0 / SLICE;
            int so = col % SLICE;
            _Float16* op = outh + (size_t)sl * N_NODES * SLICE + so;
            #pragma unroll
            for (int reg = 0; reg < 4; ++reg) {
                int rowA = r0a + quad * 4 + reg;
                int rowB = r0b + quad * 4 + reg;
                if (rowA < N_NODES) op[(size_t)rowA * SLICE] = (_Float16)accA[reg];
                if (rowB < N_NODES) op[(size_t)rowB * SLICE] = (_Float16)accB[reg];
            }
        } else if (colL < 8) {
            int hd = colL & 3;
            float* sp = (colL < 4) ? ssrc : sdst;
            #pragma unroll
            for (int reg = 0; reg < 4; ++reg) {
                int rowA = r0a + quad * 4 + reg;
                int rowB = r0b + quad * 4 + reg;
                if (rowA < N_NODES) sp[rowA * NH + hd] = accA[reg];
                if (rowB < N_NODES) sp[rowB * NH + hd] = accB[reg];
            }
        }
    }
}

// ---------------- head-vectorized alpha: 16-lane group per node, all 4 heads ----------------
__global__ __launch_bounds__(256) void alpha2_k(const float* __restrict__ ssrc,
                                                const float* __restrict__ sdst,
                                                const int* __restrict__ row_ptr,
                                                const int* __restrict__ col,
                                                float* __restrict__ alpha) {
    int wv = threadIdx.x >> 6, lane = threadIdx.x & 63;
    int grp = lane >> 4, lg = lane & 15;
    int v = blockIdx.x * 16 + wv * 4 + grp;
    if (v >= N_NODES) return;
    int beg = row_ptr[v], cnt = row_ptr[v + 1] - beg;
    f4 sdv = *(const f4*)(sdst + v * NH);
    float* pl0 = alpha + beg;
    float* pl1 = alpha + (size_t)E_TOT + beg;
    float* pl2 = alpha + (size_t)2 * E_TOT + beg;
    float* pl3 = alpha + (size_t)3 * E_TOT + beg;

    if (cnt <= 64) {
        f4 er[4];
        f4 m = {-FLT_MAX, -FLT_MAX, -FLT_MAX, -FLT_MAX};
        #pragma unroll
        for (int i = 0; i < 4; ++i) {
            int j = lg + i * 16;
            if (j < cnt) {
                int u = col[beg + j];
                f4 e = *(const f4*)(ssrc + u * NH) + sdv;
                #pragma unroll
                for (int c = 0; c < 4; ++c) e[c] = (e[c] > 0.f) ? e[c] : 0.2f * e[c];
                er[i] = e;
                #pragma unroll
                for (int c = 0; c < 4; ++c) m[c] = fmaxf(m[c], e[c]);
            }
        }
        #pragma unroll
        for (int off = 1; off < 16; off <<= 1)
            #pragma unroll
            for (int c = 0; c < 4; ++c) m[c] = fmaxf(m[c], __shfl_xor(m[c], off));
        f4 den = {};
        #pragma unroll
        for (int i = 0; i < 4; ++i) {
            int j = lg + i * 16;
            if (j < cnt) {
                f4 w;
                #pragma unroll
                for (int c = 0; c < 4; ++c) w[c] = __expf(er[i][c] - m[c]);
                er[i] = w;
                den += w;
            }
        }
        #pragma unroll
        for (int off = 1; off < 16; off <<= 1)
            #pragma unroll
            for (int c = 0; c < 4; ++c) den[c] += __shfl_xor(den[c], off);
        f4 inv;
        #pragma unroll
        for (int c = 0; c < 4; ++c) inv[c] = 1.f / (den[c] + 1e-16f);
        #pragma unroll
        for (int i = 0; i < 4; ++i) {
            int j = lg + i * 16;
            if (j < cnt) {
                pl0[j] = er[i][0] * inv[0];
                pl1[j] = er[i][1] * inv[1];
                pl2[j] = er[i][2] * inv[2];
                pl3[j] = er[i][3] * inv[3];
            }
        }
    } else {
        f4 m = {-FLT_MAX, -FLT_MAX, -FLT_MAX, -FLT_MAX};
        for (int j = lg; j < cnt; j += 16) {
            int u = col[beg + j];
            f4 e = *(const f4*)(ssrc + u * NH) + sdv;
            #pragma unroll
            for (int c = 0; c < 4; ++c) {
                e[c] = (e[c] > 0.f) ? e[c] : 0.2f * e[c];
                m[c] = fmaxf(m[c], e[c]);
            }
        }
        #pragma unroll
        for (int off = 1; off < 16; off <<= 1)
            #pragma unroll
            for (int c = 0; c < 4; ++c) m[c] = fmaxf(m[c], __shfl_xor(m[c], off));
        f4 den = {};
        for (int j = lg; j < cnt; j += 16) {
            int u = col[beg + j];
            f4 e = *(const f4*)(ssrc + u * NH) + sdv;
            #pragma unroll
            for (int c = 0; c < 4; ++c) {
                e[c] = (e[c] > 0.f) ? e[c] : 0.2f * e[c];
                den[c] += __expf(e[c] - m[c]);
            }
        }
        #pragma unroll
        for (int off = 1; off < 16; off <<= 1)
            #pragma unroll
            for (int c = 0; c < 4; ++c) den[c] += __shfl_xor(den[c], off);
        f4 inv;
        #pragma unroll
        for (int c = 0; c < 4; ++c) inv[c] = 1.f / (den[c] + 1e-16f);
        for (int j = lg; j < cnt; j += 16) {
            int u = col[beg + j];
            f4 e = *(const f4*)(ssrc + u * NH) + sdv;
            #pragma unroll
            for (int c = 0; c < 4; ++c) e[c] = (e[c] > 0.f) ? e[c] : 0.2f * e[c];
            pl0[j] = __expf(e[0] - m[0]) * inv[0];
            pl1[j] = __expf(e[1] - m[1]) * inv[1];
            pl2[j] = __expf(e[2] - m[2]) * inv[2];
            pl3[j] = __expf(e[3] - m[3]) * inv[3];
        }
    }
}

// ---------------- XCD-sharded aggregation v4 ----------------
template<int HFo, int SLICE, int LPN>
__global__ __launch_bounds__(256) void agg4_k(const _Float16* __restrict__ hh,
                                              const float* __restrict__ alpha,
                                              const int* __restrict__ row_ptr,
                                              const int* __restrict__ col,
                                              const float* __restrict__ bias,
                                              _Float16* __restrict__ outH) {
    constexpr int Fo   = HFo / NH;
    constexpr int NPW  = 64 / LPN;
    constexpr int NPB  = 4 * NPW;
    constexpr int CAPW = NPW * 32;
    __shared__ int2 prS[4][CAPW];
    int s = blockIdx.x & 7;
    int g = blockIdx.x >> 3;
    int wv = threadIdx.x >> 6, lane = threadIdx.x & 63;
    int sub = lane / LPN, lq = lane % LPN;
    int vFirst = g * NPB + wv * NPW;
    if (vFirst >= N_NODES) return;
    int vCount = min(NPW, N_NODES - vFirst);
    int hd = (s * SLICE) / Fo;
    const float* ap = alpha + (size_t)hd * E_TOT;
    int begW = row_ptr[vFirst];
    int endW = row_ptr[vFirst + vCount];
    int len = endW - begW;
    bool active = sub < vCount;
    int v = vFirst + sub;
    int beg = 0, cnt = 0;
    if (active) { beg = row_ptr[v]; cnt = row_ptr[v + 1] - beg; }
    const _Float16* base = hh + (size_t)s * N_NODES * SLICE;  // wave-uniform
    unsigned fo = (unsigned)(lq * 8);
    float acc[8] = {};

    if (len <= CAPW) {
        for (int t = lane; t < len; t += 64)
            prS[wv][t] = make_int2(col[begW + t], __float_as_int(ap[begW + t]));
        __builtin_amdgcn_wave_barrier();
        int off = beg - begW;
        int j = 0;
        for (; j + 8 <= cnt; j += 8) {
            int u[8]; float w[8]; h8v hv[8];
            #pragma unroll
            for (int i = 0; i < 8; ++i) {
                int2 q = prS[wv][off + j + i];
                u[i] = q.x; w[i] = __int_as_float(q.y);
            }
            #pragma unroll
            for (int i = 0; i < 8; ++i)
                hv[i] = *(const h8v*)(base + ((unsigned)(u[i] * SLICE) + fo));
            #pragma unroll
            for (int i = 0; i < 8; ++i)
                #pragma unroll
                for (int c = 0; c < 8; ++c) acc[c] += w[i] * (float)hv[i][c];
        }
        for (; j < cnt; ++j) {
            int2 q = prS[wv][off + j];
            float w = __int_as_float(q.y);
            h8v hv = *(const h8v*)(base + ((unsigned)(q.x * SLICE) + fo));
            #pragma unroll
            for (int c = 0; c < 8; ++c) acc[c] += w * (float)hv[c];
        }
    } else {
        const int*   cp = col + beg;
        const float* app = ap + beg;
        for (int j = 0; j < cnt; ++j) {
            int u = cp[j];
            float w = app[j];
            h8v hv = *(const h8v*)(base + ((unsigned)(u * SLICE) + fo));
            #pragma unroll
            for (int c = 0; c < 8; ++c) acc[c] += w * (float)hv[c];
        }
    }
    if (active) {
        int f0 = s * SLICE + lq * 8;
        h8v res;
        #pragma unroll
        for (int c = 0; c < 8; ++c) res[c] = (_Float16)fmaxf(acc[c] + bias[f0 + c], 0.f);
        *(h8v*)(outH + (size_t)v * HFo + f0) = res;
    }
}

// ---------------- pooling (fp16 h2v loads; batch sorted -> run-length pre-agg) ----------------
__global__ void pool_k(const _Float16* __restrict__ h, const int* __restrict__ batch,
                       float* __restrict__ gsum, float* __restrict__ gmax) {
    int f2 = threadIdx.x * 2;  // 128 threads, 2 features each
    int n0 = blockIdx.x * 32;
    int nend = min(n0 + 32, N_NODES);
    int cur = -1;
    float sa0 = 0.f, sa1 = 0.f, ma0 = 0.f, ma1 = 0.f;
    for (int n = n0; n < nend; ++n) {
        int g = batch[n];
        h2v val = *(const h2v*)(h + (size_t)n * 256 + f2);
        float v0 = (float)val[0], v1 = (float)val[1];
        if (g != cur) {
            if (cur >= 0) {
                atomicAdd(&gsum[cur * 256 + f2], sa0);
                atomicAdd(&gsum[cur * 256 + f2 + 1], sa1);
                atomicMax((int*)&gmax[cur * 256 + f2], __float_as_int(ma0));
                atomicMax((int*)&gmax[cur * 256 + f2 + 1], __float_as_int(ma1));
            }
            cur = g; sa0 = sa1 = 0.f; ma0 = ma1 = 0.f;
        }
        sa0 += v0; sa1 += v1;
        ma0 = fmaxf(ma0, v0); ma1 = fmaxf(ma1, v1);
    }
    if (cur >= 0) {
        atomicAdd(&gsum[cur * 256 + f2], sa0);
        atomicAdd(&gsum[cur * 256 + f2 + 1], sa1);
        atomicMax((int*)&gmax[cur * 256 + f2], __float_as_int(ma0));
        atomicMax((int*)&gmax[cur * 256 + f2 + 1], __float_as_int(ma1));
    }
}

// readout with fused per-graph count (batch sorted -> binary search)
__global__ void readout_k(const float* __restrict__ gsum, const float* __restrict__ gmax,
                          const int* __restrict__ batch, const float* __restrict__ Wout,
                          const float* __restrict__ bout, float* __restrict__ out) {
    int g = blockIdx.x, lane = threadIdx.x;
    int lo = 0, hi = N_NODES;
    while (lo < hi) { int mid = (lo + hi) >> 1; if (batch[mid] < g) lo = mid + 1; else hi = mid; }
    int b0 = lo;
    lo = 0; hi = N_NODES;
    while (lo < hi) { int mid = (lo + hi) >> 1; if (batch[mid] < g + 1) lo = mid + 1; else hi = mid; }
    float inv = 1.f / fmaxf((float)(lo - b0), 1.f);
    float acc[10];
    #pragma unroll
    for (int j = 0; j < 10; ++j) acc[j] = 0.f;
    for (int f = lane; f < 512; f += 64) {
        float p = (f < 256) ? gsum[g * 256 + f] * inv : gmax[g * 256 + (f - 256)];
        #pragma unroll
        for (int j = 0; j < 10; ++j) acc[j] += p * Wout[f * 10 + j];
    }
    #pragma unroll
    for (int j = 0; j < 10; ++j) {
        float a = acc[j];
        #pragma unroll
        for (int off = 32; off; off >>= 1) a += __shfl_xor(a, off);
        if (lane == 0) out[g * 10 + j] = a + bout[j];
    }
}

extern "C" void kernel_launch(void* const* d_in, const int* in_sizes, int n_in,
                              void* d_out, int out_size, void* d_ws, size_t ws_size,
                              hipStream_t stream) {
    const float* x    = (const float*)d_in[0];
    const int*   ei   = (const int*)d_in[1];
    const int*   batch= (const int*)d_in[2];
    const float* W0   = (const float*)d_in[3];
    const float* as0  = (const float*)d_in[4];
    const float* ad0  = (const float*)d_in[5];
    const float* b0   = (const float*)d_in[6];
    const float* W1   = (const float*)d_in[7];
    const float* as1  = (const float*)d_in[8];
    const float* ad1  = (const float*)d_in[9];
    const float* b1   = (const float*)d_in[10];
    const float* W2   = (const float*)d_in[11];
    const float* as2  = (const float*)d_in[12];
    const float* ad2  = (const float*)d_in[13];
    const float* b2   = (const float*)d_in[14];
    const float* Wout = (const float*)d_in[15];
    const float* bout = (const float*)d_in[16];
    float* out = (float*)d_out;

    char* ws = (char*)d_ws;
    size_t o = 0;
    auto take = [&](size_t bytes) { size_t r = o; o += (bytes + 255) & ~(size_t)255; return r; };
    size_t cnt_o  = take((size_t)N_NODES * 4);
    size_t gsum_o = take((size_t)NG * 256 * 4);
    size_t gmax_o = take((size_t)NG * 256 * 4);
    size_t zero_bytes = o;
    size_t rp_o   = take((size_t)(N_NODES + 1) * 4);
    size_t cur_o  = take((size_t)N_NODES * 4);
    size_t bsum_o = take((size_t)64 * 4);
    size_t col_o  = take((size_t)E_TOT * 4);
    size_t ssrc_o = take((size_t)N_NODES * NH * 4);
    size_t sdst_o = take((size_t)N_NODES * NH * 4);
    size_t alp_o  = take((size_t)NH * E_TOT * 4);      // per-head alpha planes
    size_t hh_o   = take((size_t)N_NODES * 256 * 2);   // fp16 h slice-major (gather)
    size_t bufH_o = take((size_t)N_NODES * 256 * 2);   // fp16 h row-major (gemm/pool in)
    size_t wp0_o  = take((size_t)(8 + 1) * 4 * 64 * 8 * 2);   // packed W + score tile
    size_t wp1_o  = take((size_t)(16 + 1) * 4 * 64 * 8 * 2);
    size_t wp2_o  = take((size_t)(16 + 1) * 8 * 64 * 8 * 2);

    int*      cnt    = (int*)(ws + cnt_o);
    float*    gsum   = (float*)(ws + gsum_o);
    float*    gmax   = (float*)(ws + gmax_o);
    int*      row_ptr= (int*)(ws + rp_o);
    int*      cursor = (int*)(ws + cur_o);
    int*      bsum   = (int*)(ws + bsum_o);
    int*      col    = (int*)(ws + col_o);
    float*    ssrc   = (float*)(ws + ssrc_o);
    float*    sdst   = (float*)(ws + sdst_o);
    float*    alpha  = (float*)(ws + alp_o);
    _Float16* hH     = (_Float16*)(ws + hh_o);
    _Float16* bufH   = (_Float16*)(ws + bufH_o);
    _Float16* Wp0    = (_Float16*)(ws + wp0_o);
    _Float16* Wp1    = (_Float16*)(ws + wp1_o);
    _Float16* Wp2    = (_Float16*)(ws + wp2_o);

    (void)hipMemsetAsync(ws, 0, zero_bytes, stream);

    count_dst_k<<<(E_TOT + 255) / 256, 256, 0, stream>>>(ei, cnt);
    scan_sums_k<<<64, 256, 0, stream>>>(cnt, bsum);
    scan_off_k<<<1, 64, 0, stream>>>(bsum, row_ptr);
    scan_write_k<<<64, 256, 0, stream>>>(cnt, bsum, row_ptr, cursor);
    fill_k<<<(E_TOT + 255) / 256, 256, 0, stream>>>(ei, cursor, col);

    // weight packing + score-tile folds (merged launches)
    pack_w_all_k<<<56, 256, 0, stream>>>(W0, W1, W2, Wp0, Wp1, Wp2);
    pack_a_all_k<<<4, 256, 0, stream>>>(W0, as0, ad0, Wp0, W1, as1, ad1, Wp1,
                                        W2, as2, ad2, Wp2);

    int gemm0_grid = (N_NODES + 63) / 64;
    int gemmh_grid = (N_NODES + 127) / 128;
    int alpha_grid = (N_NODES + 15) / 16;
    int agg128_grid = 8 * ((N_NODES + 127) / 128);
    int agg256_grid = 8 * ((N_NODES + 63) / 64);

    // layer 0: 128 -> H4*Fo32 (128)
    gemm_k<128, 128><<<gemm0_grid, 256, 0, stream>>>(x, Wp0, hH, ssrc, sdst);
    alpha2_k<<<alpha_grid, 256, 0, stream>>>(ssrc, sdst, row_ptr, col, alpha);
    agg4_k<128, 16, 2><<<agg128_grid, 256, 0, stream>>>(hH, alpha, row_ptr, col, b0, bufH);

    // layer 1: 128 -> H4*Fo64 (256)
    gemm_h_k<128, 256><<<gemmh_grid, 256, 0, stream>>>(bufH, Wp1, hH, ssrc, sdst);
    alpha2_k<<<alpha_grid, 256, 0, stream>>>(ssrc, sdst, row_ptr, col, alpha);
    agg4_k<256, 32, 4><<<agg256_grid, 256, 0, stream>>>(hH, alpha, row_ptr, col, b1, bufH);

    // layer 2: 256 -> H4*Fo64 (256)
    gemm_h_k<256, 256><<<gemmh_grid, 256, 0, stream>>>(bufH, Wp2, hH, ssrc, sdst);
    alpha2_k<<<alpha_grid, 256, 0, stream>>>(ssrc, sdst, row_ptr, col, alpha);
    agg4_k<256, 32, 4><<<agg256_grid, 256, 0, stream>>>(hH, alpha, row_ptr, col, b2, bufH);

    // pooling + readout (gcnt fused into readout)
    pool_k<<<(N_NODES + 31) / 32, 128, 0, stream>>>(bufH, batch, gsum, gmax);
    readout_k<<<NG, 64, 0, stream>>>(gsum, gmax, batch, Wout, bout, out);
}